// Round 1
// baseline (633.020 us; speedup 1.0000x reference)
//
#include <hip/hip_runtime.h>
#include <hip/hip_bf16.h>

// 2-layer GCN: out = A_hat @ relu(A_hat @ (x@W1) + b1) @ W2 + b2
// A_hat = D^-1/2 (A + I) D^-1/2, aggregation by dst over edges + self loops.
// Strategy: factor norms -> hs[n] = dinv[n]*(x@W)[n]; agg[d] = dinv[d]*(hs[d] + sum_{s in N(d)} hs[s]) + b.
// CSR-by-dst build avoids 300M fp32 atomics; node-parallel gather is conflict-free & coalesced.

static constexpr int N_NODES = 50000;
static constexpr int N_EDGES = 800000;
static constexpr int F_IN = 128;
static constexpr int HID  = 256;
static constexpr int F_OUT = 128;

__global__ void deg_kernel(const int* __restrict__ dst, int* __restrict__ deg, int E) {
    int i = blockIdx.x * blockDim.x + threadIdx.x;
    if (i < E) atomicAdd(&deg[dst[i]], 1);
}

__global__ void dinv_kernel(const int* __restrict__ deg, float* __restrict__ dinv, int N) {
    int i = blockIdx.x * blockDim.x + threadIdx.x;
    if (i < N) dinv[i] = rsqrtf((float)(deg[i] + 1));  // +1 = self loop
}

// Single-block two-level exclusive scan of edge-degree counts -> CSR row offsets.
__global__ __launch_bounds__(1024) void scan_kernel(const int* __restrict__ deg,
                                                    int* __restrict__ off, int N) {
    __shared__ int sums[1024];
    const int tid = threadIdx.x;
    const int chunk = (N + 1023) >> 10;
    const int start = tid * chunk;
    const int end = min(start + chunk, N);
    int s = 0;
    for (int i = start; i < end; i++) s += deg[i];
    sums[tid] = s;
    __syncthreads();
    for (int ofs = 1; ofs < 1024; ofs <<= 1) {
        int v = (tid >= ofs) ? sums[tid - ofs] : 0;
        __syncthreads();
        sums[tid] += v;
        __syncthreads();
    }
    int run = (tid == 0) ? 0 : sums[tid - 1];
    for (int i = start; i < end; i++) { off[i] = run; run += deg[i]; }
    if (tid == 0) off[N] = sums[1023];
}

__global__ void fill_kernel(const int* __restrict__ src, const int* __restrict__ dst,
                            const int* __restrict__ off, int* __restrict__ fill,
                            int* __restrict__ csr, int E) {
    int i = blockIdx.x * blockDim.x + threadIdx.x;
    if (i < E) {
        int d = dst[i];
        int p = atomicAdd(&fill[d], 1);
        csr[off[d] + p] = src[i];
    }
}

// out[n,f] = dinv[n] * sum_k X[n,k]*W[k,f].  Register-blocked: each thread owns
// 8 rows x 4 consecutive cols -> 32 FMA per (1 ds_read_b128 + 1 global dwordx4-ish).
// Layer1: K=128,F=256 -> CT=64 (full wave per row-group: LDS reads broadcast).
// Layer2: K=256,F=128 -> CT=32 (2 rows/wave, same-bank pair = free 2-way).
template <int K, int F, int RT>
__global__ void gemm_scale_kernel(const float* __restrict__ X, const float* __restrict__ W,
                                  const float* __restrict__ dinv, float* __restrict__ out,
                                  int N) {
    constexpr int CT = F / 4;        // col-threads
    constexpr int RPT = 8;           // rows per thread
    constexpr int RB = RT * RPT;     // rows per block
    constexpr int NT = CT * RT;      // threads per block
    __shared__ float xs[RB * K];

    const int tid = threadIdx.x;
    const int row0 = blockIdx.x * RB;
    const int nrows = min(RB, N - row0);

    // cooperative float4 stage of the X tile
    const int nvec = (nrows * K) / 4;
    const float4* Xv = (const float4*)(X + (size_t)row0 * K);
    float4* xsv = (float4*)xs;
    for (int i = tid; i < nvec; i += NT) xsv[i] = Xv[i];
    __syncthreads();

    const int ct = tid % CT;
    const int rt = tid / CT;
    const int f4 = ct * 4;
    const int r0 = rt * RPT;

    float4 acc[RPT];
#pragma unroll
    for (int r = 0; r < RPT; r++) acc[r] = make_float4(0.f, 0.f, 0.f, 0.f);

    for (int k = 0; k < K; k += 4) {
        float4 w0 = *(const float4*)&W[(k + 0) * F + f4];
        float4 w1 = *(const float4*)&W[(k + 1) * F + f4];
        float4 w2 = *(const float4*)&W[(k + 2) * F + f4];
        float4 w3 = *(const float4*)&W[(k + 3) * F + f4];
#pragma unroll
        for (int r = 0; r < RPT; r++) {
            float4 xv = *(const float4*)&xs[(r0 + r) * K + k];
            acc[r].x += xv.x * w0.x + xv.y * w1.x + xv.z * w2.x + xv.w * w3.x;
            acc[r].y += xv.x * w0.y + xv.y * w1.y + xv.z * w2.y + xv.w * w3.y;
            acc[r].z += xv.x * w0.z + xv.y * w1.z + xv.z * w2.z + xv.w * w3.z;
            acc[r].w += xv.x * w0.w + xv.y * w1.w + xv.z * w2.w + xv.w * w3.w;
        }
    }
#pragma unroll
    for (int r = 0; r < RPT; r++) {
        int row = row0 + r0 + r;
        if (row < N) {
            float dv = dinv[row];
            float4 v = make_float4(acc[r].x * dv, acc[r].y * dv, acc[r].z * dv, acc[r].w * dv);
            *(float4*)&out[(size_t)row * F + f4] = v;
        }
    }
}

// One block per dst node, one thread per feature. acc starts at hs[n] (self loop).
template <int F>
__global__ void agg_kernel(const float* __restrict__ hs, const int* __restrict__ off,
                           const int* __restrict__ csr, const float* __restrict__ dinv,
                           const float* __restrict__ bias, float* __restrict__ out,
                           int N, int do_relu) {
    const int n = blockIdx.x;
    const int f = threadIdx.x;
    float acc = hs[(size_t)n * F + f];
    const int e0 = off[n];
    const int e1 = off[n + 1];
    for (int e = e0; e < e1; e++) {
        int s = csr[e];
        acc += hs[(size_t)s * F + f];
    }
    float v = acc * dinv[n] + bias[f];
    if (do_relu) v = fmaxf(v, 0.f);
    out[(size_t)n * F + f] = v;
}

extern "C" void kernel_launch(void* const* d_in, const int* in_sizes, int n_in,
                              void* d_out, int out_size, void* d_ws, size_t ws_size,
                              hipStream_t stream) {
    const float* x  = (const float*)d_in[0];
    const int*   ei = (const int*)d_in[1];   // [2,E] int32 (JAX x64 off downcasts int64)
    const float* W1 = (const float*)d_in[2];
    const float* b1 = (const float*)d_in[3];
    const float* W2 = (const float*)d_in[4];
    const float* b2 = (const float*)d_in[5];

    const int N = N_NODES;
    const int E = N_EDGES;
    const int* srcp = ei;
    const int* dstp = ei + E;

    char* base = (char*)d_ws;
    size_t o = 0;
    auto alloc = [&](size_t bytes) {
        void* p = base + o;
        o = (o + bytes + 255) & ~(size_t)255;
        return p;
    };
    int*   deg  = (int*)alloc((size_t)N * 4);
    int*   offs = (int*)alloc((size_t)(N + 1) * 4);
    int*   fill = (int*)alloc((size_t)N * 4);
    float* dinv = (float*)alloc((size_t)N * 4);
    int*   csr  = (int*)alloc((size_t)E * 4);
    float* hs1  = (float*)alloc((size_t)N * HID * 4);
    float* h2   = (float*)alloc((size_t)N * HID * 4);
    float* hs2  = hs1;  // reuse: hs1 dead after agg1; N*F_OUT*4 < N*HID*4

    hipMemsetAsync(deg, 0, (size_t)N * 4, stream);
    hipMemsetAsync(fill, 0, (size_t)N * 4, stream);

    deg_kernel<<<(E + 255) / 256, 256, 0, stream>>>(dstp, deg, E);
    dinv_kernel<<<(N + 255) / 256, 256, 0, stream>>>(deg, dinv, N);
    scan_kernel<<<1, 1024, 0, stream>>>(deg, offs, N);
    fill_kernel<<<(E + 255) / 256, 256, 0, stream>>>(srcp, dstp, offs, fill, csr, E);

    // layer 1: hs1 = dinv * (x @ W1); h2 = relu(dinv*(hs1[self]+gather) + b1)
    gemm_scale_kernel<F_IN, HID, 4><<<(N + 31) / 32, 256, 0, stream>>>(x, W1, dinv, hs1, N);
    agg_kernel<HID><<<N, HID, 0, stream>>>(hs1, offs, csr, dinv, b1, h2, N, 1);

    // layer 2: hs2 = dinv * (h2 @ W2); out = dinv*(hs2[self]+gather) + b2
    gemm_scale_kernel<HID, F_OUT, 4><<<(N + 31) / 32, 128, 0, stream>>>(h2, W2, dinv, hs2, N);
    agg_kernel<F_OUT><<<N, F_OUT, 0, stream>>>(hs2, offs, csr, dinv, b2, (float*)d_out, N, 0);
}

// Round 2
// 514.782 us; speedup vs baseline: 1.2297x; 1.2297x over previous
//
#include <hip/hip_runtime.h>
#include <hip/hip_bf16.h>

// 2-layer GCN: out = A_hat @ relu((A_hat @ X) @ W1 + b1) @ W2 + b2
// Key reorder: A_hat@(X@W1) == (A_hat@X)@W1 -> aggregate in 128-dim, not 256-dim.
// A_hat = D^-1/2 (A+I) D^-1/2 factored: xs[n]=dinv[n]*X[n]; Y[d]=dinv[d]*(xs[d]+sum xs[s]).
// Agg kernel: 8 edge-slots x 32 float4-lanes per block for 8x gather MLP.

static constexpr int N_NODES = 50000;
static constexpr int N_EDGES = 800000;
static constexpr int F_IN = 128;
static constexpr int HID  = 256;
static constexpr int F_OUT = 128;

__global__ void deg_kernel(const int* __restrict__ dst, int* __restrict__ deg, int E) {
    int i = blockIdx.x * blockDim.x + threadIdx.x;
    if (i < E) atomicAdd(&deg[dst[i]], 1);
}

__global__ void dinv_kernel(const int* __restrict__ deg, float* __restrict__ dinv, int N) {
    int i = blockIdx.x * blockDim.x + threadIdx.x;
    if (i < N) dinv[i] = rsqrtf((float)(deg[i] + 1));  // +1 = self loop
}

// xs[n,:] = dinv[n] * X[n,:]   (float4; F_IN=128 -> 32 float4 per row)
__global__ void scalex_kernel(const float* __restrict__ x, const float* __restrict__ dinv,
                              float* __restrict__ xs, int total4) {
    int i = blockIdx.x * blockDim.x + threadIdx.x;
    if (i < total4) {
        float dv = dinv[i >> 5];
        float4 v = ((const float4*)x)[i];
        v.x *= dv; v.y *= dv; v.z *= dv; v.w *= dv;
        ((float4*)xs)[i] = v;
    }
}

// Single-block two-level exclusive scan of edge-degree counts -> CSR row offsets.
__global__ __launch_bounds__(1024) void scan_kernel(const int* __restrict__ deg,
                                                    int* __restrict__ off, int N) {
    __shared__ int sums[1024];
    const int tid = threadIdx.x;
    const int chunk = (N + 1023) >> 10;
    const int start = tid * chunk;
    const int end = min(start + chunk, N);
    int s = 0;
    for (int i = start; i < end; i++) s += deg[i];
    sums[tid] = s;
    __syncthreads();
    for (int ofs = 1; ofs < 1024; ofs <<= 1) {
        int v = (tid >= ofs) ? sums[tid - ofs] : 0;
        __syncthreads();
        sums[tid] += v;
        __syncthreads();
    }
    int run = (tid == 0) ? 0 : sums[tid - 1];
    for (int i = start; i < end; i++) { off[i] = run; run += deg[i]; }
    if (tid == 0) off[N] = sums[1023];
}

__global__ void fill_kernel(const int* __restrict__ src, const int* __restrict__ dst,
                            const int* __restrict__ off, int* __restrict__ fill,
                            int* __restrict__ csr, int E) {
    int i = blockIdx.x * blockDim.x + threadIdx.x;
    if (i < E) {
        int d = dst[i];
        int p = atomicAdd(&fill[d], 1);
        csr[off[d] + p] = src[i];
    }
}

// Aggregation over 128-dim rows: out[n] = dinv[n]*(hs[n] + sum_{s in N(n)} hs[s]) (+ bias).
// Block = 256 threads = 8 edge-slots x 32 float4-lanes -> 8 gathers in flight per block.
template <int F, bool BIAS>
__global__ __launch_bounds__(256) void agg_kernel(const float* __restrict__ hs,
                                                  const int* __restrict__ off,
                                                  const int* __restrict__ csr,
                                                  const float* __restrict__ dinv,
                                                  const float* __restrict__ bias,
                                                  float* __restrict__ out, int N) {
    constexpr int V = F / 4;    // 32 float4 lanes per row
    constexpr int S = 256 / V;  // 8 edge slots
    const int n = blockIdx.x;
    const int tid = threadIdx.x;
    const int slot = tid / V;
    const int lane = tid % V;

    float4 acc = make_float4(0.f, 0.f, 0.f, 0.f);
    if (slot == 0) acc = ((const float4*)(hs + (size_t)n * F))[lane];  // self loop, issued early

    const int e0 = off[n];
    const int e1 = off[n + 1];
    for (int e = e0 + slot; e < e1; e += S) {
        int s = csr[e];
        float4 v = ((const float4*)(hs + (size_t)s * F))[lane];
        acc.x += v.x; acc.y += v.y; acc.z += v.z; acc.w += v.w;
    }

    __shared__ float4 red[256];
    red[tid] = acc;
    __syncthreads();
    if (tid < V) {
        float4 m = red[tid];
#pragma unroll
        for (int k = 1; k < S; k++) {
            float4 o = red[k * V + tid];
            m.x += o.x; m.y += o.y; m.z += o.z; m.w += o.w;
        }
        float dv = dinv[n];
        float4 r;
        if (BIAS) {
            float4 bv = ((const float4*)bias)[tid];
            r = make_float4(m.x * dv + bv.x, m.y * dv + bv.y, m.z * dv + bv.z, m.w * dv + bv.w);
        } else {
            r = make_float4(m.x * dv, m.y * dv, m.z * dv, m.w * dv);
        }
        ((float4*)(out + (size_t)n * F))[tid] = r;
    }
}

// out[n,f] = epilogue( sum_k X[n,k]*W[k,f] ).  Register-blocked: 8 rows x 4 cols / thread.
// EPI 0: *= dinv[row]    EPI 1: relu(+ bias[f])
template <int K, int F, int RT, int EPI>
__global__ void gemm_kernel(const float* __restrict__ X, const float* __restrict__ W,
                            const float* __restrict__ dinv, const float* __restrict__ bias,
                            float* __restrict__ out, int N) {
    constexpr int CT = F / 4;        // col-threads
    constexpr int RPT = 8;           // rows per thread
    constexpr int RB = RT * RPT;     // rows per block
    constexpr int NT = CT * RT;      // threads per block
    __shared__ float xs[RB * K];

    const int tid = threadIdx.x;
    const int row0 = blockIdx.x * RB;
    const int nrows = min(RB, N - row0);

    const int nvec = (nrows * K) / 4;
    const float4* Xv = (const float4*)(X + (size_t)row0 * K);
    float4* xsv = (float4*)xs;
    for (int i = tid; i < nvec; i += NT) xsv[i] = Xv[i];
    __syncthreads();

    const int ct = tid % CT;
    const int rt = tid / CT;
    const int f4 = ct * 4;
    const int r0 = rt * RPT;

    float4 acc[RPT];
#pragma unroll
    for (int r = 0; r < RPT; r++) acc[r] = make_float4(0.f, 0.f, 0.f, 0.f);

    for (int k = 0; k < K; k += 4) {
        float4 w0 = *(const float4*)&W[(k + 0) * F + f4];
        float4 w1 = *(const float4*)&W[(k + 1) * F + f4];
        float4 w2 = *(const float4*)&W[(k + 2) * F + f4];
        float4 w3 = *(const float4*)&W[(k + 3) * F + f4];
#pragma unroll
        for (int r = 0; r < RPT; r++) {
            float4 xv = *(const float4*)&xs[(r0 + r) * K + k];
            acc[r].x += xv.x * w0.x + xv.y * w1.x + xv.z * w2.x + xv.w * w3.x;
            acc[r].y += xv.x * w0.y + xv.y * w1.y + xv.z * w2.y + xv.w * w3.y;
            acc[r].z += xv.x * w0.z + xv.y * w1.z + xv.z * w2.z + xv.w * w3.z;
            acc[r].w += xv.x * w0.w + xv.y * w1.w + xv.z * w2.w + xv.w * w3.w;
        }
    }
#pragma unroll
    for (int r = 0; r < RPT; r++) {
        int row = row0 + r0 + r;
        if (row < N) {
            float4 v = acc[r];
            if (EPI == 0) {
                float dv = dinv[row];
                v.x *= dv; v.y *= dv; v.z *= dv; v.w *= dv;
            } else {
                float4 bv = *(const float4*)&bias[f4];
                v.x = fmaxf(v.x + bv.x, 0.f);
                v.y = fmaxf(v.y + bv.y, 0.f);
                v.z = fmaxf(v.z + bv.z, 0.f);
                v.w = fmaxf(v.w + bv.w, 0.f);
            }
            *(float4*)&out[(size_t)row * F + f4] = v;
        }
    }
}

extern "C" void kernel_launch(void* const* d_in, const int* in_sizes, int n_in,
                              void* d_out, int out_size, void* d_ws, size_t ws_size,
                              hipStream_t stream) {
    const float* x  = (const float*)d_in[0];
    const int*   ei = (const int*)d_in[1];   // [2,E] int32
    const float* W1 = (const float*)d_in[2];
    const float* b1 = (const float*)d_in[3];
    const float* W2 = (const float*)d_in[4];
    const float* b2 = (const float*)d_in[5];

    const int N = N_NODES;
    const int E = N_EDGES;
    const int* srcp = ei;
    const int* dstp = ei + E;

    char* base = (char*)d_ws;
    size_t o = 0;
    auto alloc = [&](size_t bytes) {
        void* p = base + o;
        o = (o + bytes + 255) & ~(size_t)255;
        return p;
    };
    int*   deg  = (int*)alloc((size_t)N * 4);
    int*   offs = (int*)alloc((size_t)(N + 1) * 4);
    int*   fill = (int*)alloc((size_t)N * 4);
    float* dinv = (float*)alloc((size_t)N * 4);
    int*   csr  = (int*)alloc((size_t)E * 4);
    float* xs   = (float*)alloc((size_t)N * F_IN * 4);   // dinv*X, then reused for hs2
    float* Y    = (float*)alloc((size_t)N * F_IN * 4);   // A_hat @ X
    float* h2   = (float*)alloc((size_t)N * HID * 4);    // relu(Y@W1+b1)
    float* hs2  = xs;  // xs dead after agg1

    hipMemsetAsync(deg, 0, (size_t)N * 4, stream);
    hipMemsetAsync(fill, 0, (size_t)N * 4, stream);

    deg_kernel<<<(E + 255) / 256, 256, 0, stream>>>(dstp, deg, E);
    dinv_kernel<<<(N + 255) / 256, 256, 0, stream>>>(deg, dinv, N);
    scan_kernel<<<1, 1024, 0, stream>>>(deg, offs, N);
    fill_kernel<<<(E + 255) / 256, 256, 0, stream>>>(srcp, dstp, offs, fill, csr, E);
    scalex_kernel<<<(N * F_IN / 4 + 255) / 256, 256, 0, stream>>>(x, dinv, xs, N * F_IN / 4);

    // layer 1: Y = A_hat@X (128-dim agg); h2 = relu(Y@W1 + b1)
    agg_kernel<F_IN, false><<<N, 256, 0, stream>>>(xs, offs, csr, dinv, nullptr, Y, N);
    gemm_kernel<F_IN, HID, 4, 1><<<(N + 31) / 32, 256, 0, stream>>>(Y, W1, nullptr, b1, h2, N);

    // layer 2: hs2 = dinv*(h2@W2); out = dinv*(hs2[self]+gather) + b2
    gemm_kernel<HID, F_OUT, 4, 0><<<(N + 31) / 32, 128, 0, stream>>>(h2, W2, dinv, nullptr, hs2, N);
    agg_kernel<F_OUT, true><<<N, 256, 0, stream>>>(hs2, offs, csr, dinv, b2, (float*)d_out, N);
}

// Round 3
// 434.450 us; speedup vs baseline: 1.4571x; 1.1849x over previous
//
#include <hip/hip_runtime.h>
#include <hip/hip_bf16.h>

// 2-layer GCN: out = A_hat @ relu((A_hat@X)@W1 + b1) @ W2 + b2,  A_hat = D^-1/2 (A+I) D^-1/2
// R3: bf16 activation pipeline. Gathers move bf16 rows (halves LLC-bound agg bytes);
// GEMMs use mfma_f32_16x16x32_bf16 with fp32 accumulation, LDS-free (W^T is 64 KB,
// L1/L2-resident). All reductions accumulate in fp32; final output fp32.

static constexpr int N_NODES = 50000;
static constexpr int N_EDGES = 800000;
static constexpr int F_IN = 128;
static constexpr int HID  = 256;
static constexpr int F_OUT = 128;

typedef __attribute__((ext_vector_type(8))) short short8;   // 8 bf16 raw bits (4 VGPRs)
typedef __attribute__((ext_vector_type(4))) float f32x4;

__device__ __forceinline__ unsigned short f2bf(float f) {   // RNE fp32->bf16
    union { float f; unsigned u; } x; x.f = f;
    unsigned r = x.u + 0x7FFF + ((x.u >> 16) & 1);
    return (unsigned short)(r >> 16);
}
__device__ __forceinline__ float bf2f(unsigned short h) {
    union { unsigned u; float f; } x; x.u = ((unsigned)h) << 16;
    return x.f;
}

__global__ void deg_kernel(const int* __restrict__ dst, int* __restrict__ deg, int E) {
    int i = blockIdx.x * blockDim.x + threadIdx.x;
    if (i < E) atomicAdd(&deg[dst[i]], 1);
}

__global__ void dinv_kernel(const int* __restrict__ deg, float* __restrict__ dinv, int N) {
    int i = blockIdx.x * blockDim.x + threadIdx.x;
    if (i < N) dinv[i] = rsqrtf((float)(deg[i] + 1));  // +1 = self loop
}

// Single-block two-level exclusive scan of edge-degree counts -> CSR row offsets.
__global__ __launch_bounds__(1024) void scan_kernel(const int* __restrict__ deg,
                                                    int* __restrict__ off, int N) {
    __shared__ int sums[1024];
    const int tid = threadIdx.x;
    const int chunk = (N + 1023) >> 10;
    const int start = tid * chunk;
    const int end = min(start + chunk, N);
    int s = 0;
    for (int i = start; i < end; i++) s += deg[i];
    sums[tid] = s;
    __syncthreads();
    for (int ofs = 1; ofs < 1024; ofs <<= 1) {
        int v = (tid >= ofs) ? sums[tid - ofs] : 0;
        __syncthreads();
        sums[tid] += v;
        __syncthreads();
    }
    int run = (tid == 0) ? 0 : sums[tid - 1];
    for (int i = start; i < end; i++) { off[i] = run; run += deg[i]; }
    if (tid == 0) off[N] = sums[1023];
}

__global__ void fill_kernel(const int* __restrict__ src, const int* __restrict__ dst,
                            const int* __restrict__ off, int* __restrict__ fill,
                            int* __restrict__ csr, int E) {
    int i = blockIdx.x * blockDim.x + threadIdx.x;
    if (i < E) {
        int d = dst[i];
        int p = atomicAdd(&fill[d], 1);
        csr[off[d] + p] = src[i];
    }
}

// xs[n,:] = bf16( dinv[n] * X[n,:] ).  One thread per 8 elements.
__global__ void scalex_kernel(const float* __restrict__ x, const float* __restrict__ dinv,
                              unsigned short* __restrict__ xs, int n8) {
    int i = blockIdx.x * blockDim.x + threadIdx.x;
    if (i < n8) {
        float dv = dinv[i >> 4];                 // 16 groups of 8 per 128-row
        float4 v0 = ((const float4*)x)[i * 2];
        float4 v1 = ((const float4*)x)[i * 2 + 1];
        short8 o;
        o[0] = (short)f2bf(v0.x * dv); o[1] = (short)f2bf(v0.y * dv);
        o[2] = (short)f2bf(v0.z * dv); o[3] = (short)f2bf(v0.w * dv);
        o[4] = (short)f2bf(v1.x * dv); o[5] = (short)f2bf(v1.y * dv);
        o[6] = (short)f2bf(v1.z * dv); o[7] = (short)f2bf(v1.w * dv);
        *(short8*)(xs + (size_t)i * 8) = o;
    }
}

// WT[n][k] = bf16( W[k][n] )  (transpose for k-contiguous B fragments)
__global__ void wt_kernel(const float* __restrict__ W, unsigned short* __restrict__ WT,
                          int K, int N) {
    int t = blockIdx.x * blockDim.x + threadIdx.x;
    if (t < K * N) {
        int n = t / K, k = t - n * K;
        WT[t] = f2bf(W[(size_t)k * N + n]);
    }
}

// Aggregation over 128-dim bf16 rows, fp32 accumulate.
// Block = 256 threads = 16 edge-slots x 16 lanes (ushort8 / 16 B per lane).
// MODE 0: out_bf16[n] = bf16( dinv[n] * (self + sum) )
// MODE 1: out_f32[n]  = dinv[n] * (self + sum) + bias
template <int MODE>
__global__ __launch_bounds__(256) void agg_bf16(const unsigned short* __restrict__ hs,
                                                const int* __restrict__ off,
                                                const int* __restrict__ csr,
                                                const float* __restrict__ dinv,
                                                const float* __restrict__ bias,
                                                void* __restrict__ outp, int N) {
    const int n = blockIdx.x;
    const int tid = threadIdx.x;
    const int lane16 = tid & 15;
    const int slot = tid >> 4;

    float va[8];
#pragma unroll
    for (int j = 0; j < 8; j++) va[j] = 0.f;

    if (slot == 0) {  // self loop
        short8 s = *(const short8*)(hs + (size_t)n * 128 + lane16 * 8);
#pragma unroll
        for (int j = 0; j < 8; j++) va[j] = bf2f((unsigned short)s[j]);
    }

    const int e0 = off[n];
    const int e1 = off[n + 1];
    for (int e = e0 + slot; e < e1; e += 16) {
        int s = csr[e];
        short8 v = *(const short8*)(hs + (size_t)s * 128 + lane16 * 8);
#pragma unroll
        for (int j = 0; j < 8; j++) va[j] += bf2f((unsigned short)v[j]);
    }

    // wave-level: 4 slots per wave -> lanes 0..15 hold wave partial
#pragma unroll
    for (int j = 0; j < 8; j++) va[j] += __shfl_down(va[j], 32);
#pragma unroll
    for (int j = 0; j < 8; j++) va[j] += __shfl_down(va[j], 16);

    __shared__ float red[4][16][8];
    const int wid = tid >> 6;
    if ((tid & 63) < 16) {
#pragma unroll
        for (int j = 0; j < 8; j++) red[wid][lane16][j] = va[j];
    }
    __syncthreads();

    if (tid < 16) {
        float r[8];
#pragma unroll
        for (int j = 0; j < 8; j++)
            r[j] = red[0][tid][j] + red[1][tid][j] + red[2][tid][j] + red[3][tid][j];
        float dv = dinv[n];
        if (MODE == 0) {
            short8 o;
#pragma unroll
            for (int j = 0; j < 8; j++) o[j] = (short)f2bf(r[j] * dv);
            *(short8*)((unsigned short*)outp + (size_t)n * 128 + tid * 8) = o;
        } else {
            float* op = (float*)outp + (size_t)n * 128 + tid * 8;
            float4 o0, o1;
            o0.x = r[0] * dv + bias[tid * 8 + 0];
            o0.y = r[1] * dv + bias[tid * 8 + 1];
            o0.z = r[2] * dv + bias[tid * 8 + 2];
            o0.w = r[3] * dv + bias[tid * 8 + 3];
            o1.x = r[4] * dv + bias[tid * 8 + 4];
            o1.y = r[5] * dv + bias[tid * 8 + 5];
            o1.z = r[6] * dv + bias[tid * 8 + 6];
            o1.w = r[7] * dv + bias[tid * 8 + 7];
            ((float4*)op)[0] = o0;
            ((float4*)op)[1] = o1;
        }
    }
}

// bf16 MFMA GEMM, LDS-free. out[m][col] = epi( sum_k X[m][k] * WT[col][k] ).
// Wave = one 16-row strip; A frags preloaded (K/32 x short8); B frags streamed from
// global WT (64 KB, L1/L2-resident, reused by all blocks). fp32 accumulate.
// A layout: m=lane&15, k=(lane>>4)*8+j.  B layout: n=lane&15, k=(lane>>4)*8+j.
// D layout: col=lane&15, row=(lane>>4)*4+reg   [measured: learn_hip m89/m91]
// EPI 1: relu(v + bias[col]) -> bf16.  EPI 0: v * dinv[m] -> bf16.
template <int K, int NC, int EPI>
__global__ __launch_bounds__(256) void mfma_gemm(const unsigned short* __restrict__ X,
                                                 const unsigned short* __restrict__ WT,
                                                 const float* __restrict__ bias,
                                                 const float* __restrict__ dinv,
                                                 unsigned short* __restrict__ out, int M) {
    constexpr int KC = K / 32;
    const int wid = threadIdx.x >> 6;
    const int lane = threadIdx.x & 63;
    const int m0 = blockIdx.x * 64 + wid * 16;
    const int an = lane & 15;
    const int q = lane >> 4;

    int arow = m0 + an;
    if (arow >= M) arow = M - 1;  // clamp (harmless duplicate row for OOB waves)
    const unsigned short* xp = X + (size_t)arow * K + q * 8;
    short8 a[KC];
#pragma unroll
    for (int c = 0; c < KC; c++) a[c] = *(const short8*)(xp + c * 32);

    for (int nt = 0; nt < NC / 16; nt++) {
        f32x4 acc = {0.f, 0.f, 0.f, 0.f};
        const unsigned short* wp = WT + (size_t)(nt * 16 + an) * K + q * 8;
#pragma unroll
        for (int c = 0; c < KC; c++) {
            short8 b = *(const short8*)(wp + c * 32);
            acc = __builtin_amdgcn_mfma_f32_16x16x32_bf16(a[c], b, acc, 0, 0, 0);
        }
        const int col = nt * 16 + an;
#pragma unroll
        for (int r = 0; r < 4; r++) {
            int m = m0 + q * 4 + r;
            if (m < M) {
                float v = acc[r];
                if (EPI == 1) v = fmaxf(v + bias[col], 0.f);
                else v *= dinv[m];
                out[(size_t)m * NC + col] = f2bf(v);
            }
        }
    }
}

extern "C" void kernel_launch(void* const* d_in, const int* in_sizes, int n_in,
                              void* d_out, int out_size, void* d_ws, size_t ws_size,
                              hipStream_t stream) {
    const float* x  = (const float*)d_in[0];
    const int*   ei = (const int*)d_in[1];   // [2,E] int32
    const float* W1 = (const float*)d_in[2];
    const float* b1 = (const float*)d_in[3];
    const float* W2 = (const float*)d_in[4];
    const float* b2 = (const float*)d_in[5];

    const int N = N_NODES;
    const int E = N_EDGES;
    const int* srcp = ei;
    const int* dstp = ei + E;

    char* base = (char*)d_ws;
    size_t o = 0;
    auto alloc = [&](size_t bytes) {
        void* p = base + o;
        o = (o + bytes + 255) & ~(size_t)255;
        return p;
    };
    int*            deg  = (int*)alloc((size_t)N * 4);
    int*            offs = (int*)alloc((size_t)(N + 1) * 4);
    int*            fill = (int*)alloc((size_t)N * 4);
    float*          dinv = (float*)alloc((size_t)N * 4);
    int*            csr  = (int*)alloc((size_t)E * 4);
    unsigned short* xs   = (unsigned short*)alloc((size_t)N * F_IN * 2);  // dinv*x, bf16
    unsigned short* Y    = (unsigned short*)alloc((size_t)N * F_IN * 2);  // A_hat@X, bf16
    unsigned short* h2   = (unsigned short*)alloc((size_t)N * HID * 2);   // relu(Y@W1+b1)
    unsigned short* w1t  = (unsigned short*)alloc((size_t)F_IN * HID * 2);
    unsigned short* w2t  = (unsigned short*)alloc((size_t)HID * F_OUT * 2);
    unsigned short* hs2  = xs;  // xs dead after agg1

    hipMemsetAsync(deg, 0, (size_t)N * 4, stream);
    hipMemsetAsync(fill, 0, (size_t)N * 4, stream);

    deg_kernel<<<(E + 255) / 256, 256, 0, stream>>>(dstp, deg, E);
    dinv_kernel<<<(N + 255) / 256, 256, 0, stream>>>(deg, dinv, N);
    scan_kernel<<<1, 1024, 0, stream>>>(deg, offs, N);
    fill_kernel<<<(E + 255) / 256, 256, 0, stream>>>(srcp, dstp, offs, fill, csr, E);
    scalex_kernel<<<(N * F_IN / 8 + 255) / 256, 256, 0, stream>>>(x, dinv, xs, N * F_IN / 8);
    wt_kernel<<<(F_IN * HID + 255) / 256, 256, 0, stream>>>(W1, w1t, F_IN, HID);
    wt_kernel<<<(HID * F_OUT + 255) / 256, 256, 0, stream>>>(W2, w2t, HID, F_OUT);

    // layer 1: Y = A_hat@X (bf16 gather); h2 = relu(Y@W1 + b1)
    agg_bf16<0><<<N, 256, 0, stream>>>(xs, offs, csr, dinv, nullptr, Y, N);
    mfma_gemm<F_IN, HID, 1><<<(N + 63) / 64, 256, 0, stream>>>(Y, w1t, b1, nullptr, h2, N);

    // layer 2: hs2 = dinv*(h2@W2); out = dinv*(hs2[self]+gather) + b2
    mfma_gemm<HID, F_OUT, 0><<<(N + 63) / 64, 256, 0, stream>>>(h2, w2t, nullptr, dinv, hs2, N);
    agg_bf16<1><<<N, 256, 0, stream>>>(hs2, offs, csr, dinv, b2, d_out, N);
}

// Round 4
// 335.824 us; speedup vs baseline: 1.8850x; 1.2937x over previous
//
#include <hip/hip_runtime.h>
#include <hip/hip_bf16.h>

// 2-layer GCN: out = A_hat @ relu((A_hat@X)@W1 + b1) @ W2 + b2,  A_hat = D^-1/2 (A+I) D^-1/2
// R4: (a) multi-block CSR scan (the single-block scan was 77 us on one CU);
//     (b) wave-per-node aggregation (no LDS/barrier reduction; 4 nodes per block).
// bf16 activations/gathers, fp32 accumulation everywhere, MFMA GEMMs.

static constexpr int N_NODES = 50000;
static constexpr int N_EDGES = 800000;
static constexpr int F_IN = 128;
static constexpr int HID  = 256;
static constexpr int F_OUT = 128;

typedef __attribute__((ext_vector_type(8))) short short8;   // 8 bf16 raw bits (4 VGPRs)
typedef __attribute__((ext_vector_type(4))) float f32x4;

__device__ __forceinline__ unsigned short f2bf(float f) {   // RNE fp32->bf16
    union { float f; unsigned u; } x; x.f = f;
    unsigned r = x.u + 0x7FFF + ((x.u >> 16) & 1);
    return (unsigned short)(r >> 16);
}
__device__ __forceinline__ float bf2f(unsigned short h) {
    union { unsigned u; float f; } x; x.u = ((unsigned)h) << 16;
    return x.f;
}

__global__ void deg_kernel(const int* __restrict__ dst, int* __restrict__ deg, int E) {
    int i = blockIdx.x * blockDim.x + threadIdx.x;
    if (i < E) atomicAdd(&deg[dst[i]], 1);
}

__global__ void dinv_kernel(const int* __restrict__ deg, float* __restrict__ dinv, int N) {
    int i = blockIdx.x * blockDim.x + threadIdx.x;
    if (i < N) dinv[i] = rsqrtf((float)(deg[i] + 1));  // +1 = self loop
}

// ---- 3-phase exclusive scan of deg -> off (off[N] = E) ----
__global__ __launch_bounds__(256) void scan_reduce(const int* __restrict__ deg,
                                                   int* __restrict__ bsums, int N) {
    int i = blockIdx.x * 256 + threadIdx.x;
    int v = (i < N) ? deg[i] : 0;
#pragma unroll
    for (int ofs = 32; ofs > 0; ofs >>= 1) v += __shfl_down(v, ofs);
    __shared__ int ws[4];
    if ((threadIdx.x & 63) == 0) ws[threadIdx.x >> 6] = v;
    __syncthreads();
    if (threadIdx.x == 0) bsums[blockIdx.x] = ws[0] + ws[1] + ws[2] + ws[3];
}

__global__ __launch_bounds__(256) void scan_bsums(int* __restrict__ bsums, int nb) {
    __shared__ int s[256];
    int tid = threadIdx.x;
    s[tid] = (tid < nb) ? bsums[tid] : 0;
    __syncthreads();
    for (int ofs = 1; ofs < 256; ofs <<= 1) {
        int v = (tid >= ofs) ? s[tid - ofs] : 0;
        __syncthreads();
        s[tid] += v;
        __syncthreads();
    }
    bsums[tid] = (tid == 0) ? 0 : s[tid - 1];   // exclusive
}

__global__ __launch_bounds__(256) void scan_final(const int* __restrict__ deg,
                                                  const int* __restrict__ bsums,
                                                  int* __restrict__ off, int N) {
    __shared__ int s[256];
    const int tid = threadIdx.x;
    const int i = blockIdx.x * 256 + tid;
    int v = (i < N) ? deg[i] : 0;
    s[tid] = v;
    __syncthreads();
    for (int ofs = 1; ofs < 256; ofs <<= 1) {
        int t = (tid >= ofs) ? s[tid - ofs] : 0;
        __syncthreads();
        s[tid] += t;
        __syncthreads();
    }
    int excl = (tid == 0) ? 0 : s[tid - 1];
    if (i <= N) off[i] = bsums[blockIdx.x] + excl;
}

__global__ void fill_kernel(const int* __restrict__ src, const int* __restrict__ dst,
                            const int* __restrict__ off, int* __restrict__ fill,
                            int* __restrict__ csr, int E) {
    int i = blockIdx.x * blockDim.x + threadIdx.x;
    if (i < E) {
        int d = dst[i];
        int p = atomicAdd(&fill[d], 1);
        csr[off[d] + p] = src[i];
    }
}

// xs[n,:] = bf16( dinv[n] * X[n,:] ).  One thread per 8 elements.
__global__ void scalex_kernel(const float* __restrict__ x, const float* __restrict__ dinv,
                              unsigned short* __restrict__ xs, int n8) {
    int i = blockIdx.x * blockDim.x + threadIdx.x;
    if (i < n8) {
        float dv = dinv[i >> 4];                 // 16 groups of 8 per 128-row
        float4 v0 = ((const float4*)x)[i * 2];
        float4 v1 = ((const float4*)x)[i * 2 + 1];
        short8 o;
        o[0] = (short)f2bf(v0.x * dv); o[1] = (short)f2bf(v0.y * dv);
        o[2] = (short)f2bf(v0.z * dv); o[3] = (short)f2bf(v0.w * dv);
        o[4] = (short)f2bf(v1.x * dv); o[5] = (short)f2bf(v1.y * dv);
        o[6] = (short)f2bf(v1.z * dv); o[7] = (short)f2bf(v1.w * dv);
        *(short8*)(xs + (size_t)i * 8) = o;
    }
}

// WT[n][k] = bf16( W[k][n] )  (transpose for k-contiguous B fragments)
__global__ void wt_kernel(const float* __restrict__ W, unsigned short* __restrict__ WT,
                          int K, int N) {
    int t = blockIdx.x * blockDim.x + threadIdx.x;
    if (t < K * N) {
        int n = t / K, k = t - n * K;
        WT[t] = f2bf(W[(size_t)k * N + n]);
    }
}

// Wave-per-node aggregation over 128-dim bf16 rows, fp32 accumulate.
// Wave = 4 edge-slots x 16 lanes (ushort8 / 16 B per lane); 4 nodes per 256-block.
// Reduction: two shfl_down steps; no LDS, no barrier.
// MODE 0: out_bf16[n] = bf16( dinv[n] * (self + sum) )
// MODE 1: out_f32[n]  = dinv[n] * (self + sum) + bias
template <int MODE>
__global__ __launch_bounds__(256) void agg_bf16(const unsigned short* __restrict__ hs,
                                                const int* __restrict__ off,
                                                const int* __restrict__ csr,
                                                const float* __restrict__ dinv,
                                                const float* __restrict__ bias,
                                                void* __restrict__ outp, int N) {
    const int wid = threadIdx.x >> 6;
    const int n = blockIdx.x * 4 + wid;
    if (n >= N) return;
    const int lane = threadIdx.x & 63;
    const int lane16 = lane & 15;
    const int slot = lane >> 4;   // 0..3

    float va[8];
#pragma unroll
    for (int j = 0; j < 8; j++) va[j] = 0.f;

    if (slot == 0) {  // self loop
        short8 s = *(const short8*)(hs + (size_t)n * 128 + lane16 * 8);
#pragma unroll
        for (int j = 0; j < 8; j++) va[j] = bf2f((unsigned short)s[j]);
    }

    const int e0 = off[n];
    const int e1 = off[n + 1];
    for (int e = e0 + slot; e < e1; e += 4) {
        int s = csr[e];
        short8 v = *(const short8*)(hs + (size_t)s * 128 + lane16 * 8);
#pragma unroll
        for (int j = 0; j < 8; j++) va[j] += bf2f((unsigned short)v[j]);
    }

#pragma unroll
    for (int j = 0; j < 8; j++) va[j] += __shfl_down(va[j], 32);
#pragma unroll
    for (int j = 0; j < 8; j++) va[j] += __shfl_down(va[j], 16);

    if (lane < 16) {
        float dv = dinv[n];
        if (MODE == 0) {
            short8 o;
#pragma unroll
            for (int j = 0; j < 8; j++) o[j] = (short)f2bf(va[j] * dv);
            *(short8*)((unsigned short*)outp + (size_t)n * 128 + lane * 8) = o;
        } else {
            float* op = (float*)outp + (size_t)n * 128 + lane * 8;
            float4 o0, o1;
            o0.x = va[0] * dv + bias[lane * 8 + 0];
            o0.y = va[1] * dv + bias[lane * 8 + 1];
            o0.z = va[2] * dv + bias[lane * 8 + 2];
            o0.w = va[3] * dv + bias[lane * 8 + 3];
            o1.x = va[4] * dv + bias[lane * 8 + 4];
            o1.y = va[5] * dv + bias[lane * 8 + 5];
            o1.z = va[6] * dv + bias[lane * 8 + 6];
            o1.w = va[7] * dv + bias[lane * 8 + 7];
            ((float4*)op)[0] = o0;
            ((float4*)op)[1] = o1;
        }
    }
}

// bf16 MFMA GEMM, LDS-free. out[m][col] = epi( sum_k X[m][k] * WT[col][k] ).
// Wave = one 16-row strip; A frags preloaded; B streamed from global WT (L1/L2-resident).
// D layout: col=lane&15, row=(lane>>4)*4+reg   [measured: learn_hip m89/m91]
// EPI 1: relu(v + bias[col]) -> bf16.  EPI 0: v * dinv[m] -> bf16.
template <int K, int NC, int EPI>
__global__ __launch_bounds__(256) void mfma_gemm(const unsigned short* __restrict__ X,
                                                 const unsigned short* __restrict__ WT,
                                                 const float* __restrict__ bias,
                                                 const float* __restrict__ dinv,
                                                 unsigned short* __restrict__ out, int M) {
    constexpr int KC = K / 32;
    const int wid = threadIdx.x >> 6;
    const int lane = threadIdx.x & 63;
    const int m0 = blockIdx.x * 64 + wid * 16;
    const int an = lane & 15;
    const int q = lane >> 4;

    int arow = m0 + an;
    if (arow >= M) arow = M - 1;  // clamp (harmless duplicate row for OOB waves)
    const unsigned short* xp = X + (size_t)arow * K + q * 8;
    short8 a[KC];
#pragma unroll
    for (int c = 0; c < KC; c++) a[c] = *(const short8*)(xp + c * 32);

    for (int nt = 0; nt < NC / 16; nt++) {
        f32x4 acc = {0.f, 0.f, 0.f, 0.f};
        const unsigned short* wp = WT + (size_t)(nt * 16 + an) * K + q * 8;
#pragma unroll
        for (int c = 0; c < KC; c++) {
            short8 b = *(const short8*)(wp + c * 32);
            acc = __builtin_amdgcn_mfma_f32_16x16x32_bf16(a[c], b, acc, 0, 0, 0);
        }
        const int col = nt * 16 + an;
#pragma unroll
        for (int r = 0; r < 4; r++) {
            int m = m0 + q * 4 + r;
            if (m < M) {
                float v = acc[r];
                if (EPI == 1) v = fmaxf(v + bias[col], 0.f);
                else v *= dinv[m];
                out[(size_t)m * NC + col] = f2bf(v);
            }
        }
    }
}

extern "C" void kernel_launch(void* const* d_in, const int* in_sizes, int n_in,
                              void* d_out, int out_size, void* d_ws, size_t ws_size,
                              hipStream_t stream) {
    const float* x  = (const float*)d_in[0];
    const int*   ei = (const int*)d_in[1];   // [2,E] int32
    const float* W1 = (const float*)d_in[2];
    const float* b1 = (const float*)d_in[3];
    const float* W2 = (const float*)d_in[4];
    const float* b2 = (const float*)d_in[5];

    const int N = N_NODES;
    const int E = N_EDGES;
    const int* srcp = ei;
    const int* dstp = ei + E;

    char* base = (char*)d_ws;
    size_t o = 0;
    auto alloc = [&](size_t bytes) {
        void* p = base + o;
        o = (o + bytes + 255) & ~(size_t)255;
        return p;
    };
    int*            deg  = (int*)alloc((size_t)N * 4);
    int*            offs = (int*)alloc((size_t)(N + 1) * 4);
    int*            fill = (int*)alloc((size_t)N * 4);
    float*          dinv = (float*)alloc((size_t)N * 4);
    int*            bsum = (int*)alloc(256 * 4);
    int*            csr  = (int*)alloc((size_t)E * 4);
    unsigned short* xs   = (unsigned short*)alloc((size_t)N * F_IN * 2);  // dinv*x, bf16
    unsigned short* Y    = (unsigned short*)alloc((size_t)N * F_IN * 2);  // A_hat@X, bf16
    unsigned short* h2   = (unsigned short*)alloc((size_t)N * HID * 2);   // relu(Y@W1+b1)
    unsigned short* w1t  = (unsigned short*)alloc((size_t)F_IN * HID * 2);
    unsigned short* w2t  = (unsigned short*)alloc((size_t)HID * F_OUT * 2);
    unsigned short* hs2  = xs;  // xs dead after agg1

    hipMemsetAsync(deg, 0, (size_t)N * 4, stream);
    hipMemsetAsync(fill, 0, (size_t)N * 4, stream);

    const int NB = (N + 256) / 256;   // covers i==N in scan_final
    deg_kernel<<<(E + 255) / 256, 256, 0, stream>>>(dstp, deg, E);
    dinv_kernel<<<(N + 255) / 256, 256, 0, stream>>>(deg, dinv, N);
    scan_reduce<<<NB, 256, 0, stream>>>(deg, bsum, N);
    scan_bsums<<<1, 256, 0, stream>>>(bsum, NB);
    scan_final<<<NB, 256, 0, stream>>>(deg, bsum, offs, N);
    fill_kernel<<<(E + 255) / 256, 256, 0, stream>>>(srcp, dstp, offs, fill, csr, E);
    scalex_kernel<<<(N * F_IN / 8 + 255) / 256, 256, 0, stream>>>(x, dinv, xs, N * F_IN / 8);
    wt_kernel<<<(F_IN * HID + 255) / 256, 256, 0, stream>>>(W1, w1t, F_IN, HID);
    wt_kernel<<<(HID * F_OUT + 255) / 256, 256, 0, stream>>>(W2, w2t, HID, F_OUT);

    // layer 1: Y = A_hat@X (bf16 gather); h2 = relu(Y@W1 + b1)
    agg_bf16<0><<<(N + 3) / 4, 256, 0, stream>>>(xs, offs, csr, dinv, nullptr, Y, N);
    mfma_gemm<F_IN, HID, 1><<<(N + 63) / 64, 256, 0, stream>>>(Y, w1t, b1, nullptr, h2, N);

    // layer 2: hs2 = dinv*(h2@W2); out = dinv*(hs2[self]+gather) + b2
    mfma_gemm<HID, F_OUT, 0><<<(N + 63) / 64, 256, 0, stream>>>(h2, w2t, nullptr, dinv, hs2, N);
    agg_bf16<1><<<(N + 3) / 4, 256, 0, stream>>>(hs2, offs, csr, dinv, b2, d_out, N);
}

// Round 5
// 296.351 us; speedup vs baseline: 2.1361x; 1.1332x over previous
//
#include <hip/hip_runtime.h>
#include <hip/hip_bf16.h>

// 2-layer GCN: out = A_hat @ relu((A_hat@X)@W1 + b1) @ W2 + b2,  A_hat = D^-1/2 (A+I) D^-1/2
// R5: GEMM latency restructure -- R=2 M-blocking (2 indep MFMA chains, half the B loads),
//     col-split waves (grid stays 782 blocks / ~3 waves/SIMD), partial-unrolled tile loop
//     so B loads pipeline across tiles. Agg edge loop unrolled x2 (8 gathers in flight).
// bf16 activations/gathers, fp32 accumulation everywhere.

static constexpr int N_NODES = 50000;
static constexpr int N_EDGES = 800000;
static constexpr int F_IN = 128;
static constexpr int HID  = 256;
static constexpr int F_OUT = 128;

typedef __attribute__((ext_vector_type(8))) short short8;   // 8 bf16 raw bits (4 VGPRs)
typedef __attribute__((ext_vector_type(4))) float f32x4;

__device__ __forceinline__ unsigned short f2bf(float f) {   // RNE fp32->bf16
    union { float f; unsigned u; } x; x.f = f;
    unsigned r = x.u + 0x7FFF + ((x.u >> 16) & 1);
    return (unsigned short)(r >> 16);
}
__device__ __forceinline__ float bf2f(unsigned short h) {
    union { unsigned u; float f; } x; x.u = ((unsigned)h) << 16;
    return x.f;
}

__global__ void deg_kernel(const int* __restrict__ dst, int* __restrict__ deg, int E) {
    int i = blockIdx.x * blockDim.x + threadIdx.x;
    if (i < E) atomicAdd(&deg[dst[i]], 1);
}

__global__ void dinv_kernel(const int* __restrict__ deg, float* __restrict__ dinv, int N) {
    int i = blockIdx.x * blockDim.x + threadIdx.x;
    if (i < N) dinv[i] = rsqrtf((float)(deg[i] + 1));  // +1 = self loop
}

// ---- 3-phase exclusive scan of deg -> off (off[N] = E) ----
__global__ __launch_bounds__(256) void scan_reduce(const int* __restrict__ deg,
                                                   int* __restrict__ bsums, int N) {
    int i = blockIdx.x * 256 + threadIdx.x;
    int v = (i < N) ? deg[i] : 0;
#pragma unroll
    for (int ofs = 32; ofs > 0; ofs >>= 1) v += __shfl_down(v, ofs);
    __shared__ int ws[4];
    if ((threadIdx.x & 63) == 0) ws[threadIdx.x >> 6] = v;
    __syncthreads();
    if (threadIdx.x == 0) bsums[blockIdx.x] = ws[0] + ws[1] + ws[2] + ws[3];
}

__global__ __launch_bounds__(256) void scan_bsums(int* __restrict__ bsums, int nb) {
    __shared__ int s[256];
    int tid = threadIdx.x;
    s[tid] = (tid < nb) ? bsums[tid] : 0;
    __syncthreads();
    for (int ofs = 1; ofs < 256; ofs <<= 1) {
        int v = (tid >= ofs) ? s[tid - ofs] : 0;
        __syncthreads();
        s[tid] += v;
        __syncthreads();
    }
    bsums[tid] = (tid == 0) ? 0 : s[tid - 1];   // exclusive
}

__global__ __launch_bounds__(256) void scan_final(const int* __restrict__ deg,
                                                  const int* __restrict__ bsums,
                                                  int* __restrict__ off, int N) {
    __shared__ int s[256];
    const int tid = threadIdx.x;
    const int i = blockIdx.x * 256 + tid;
    int v = (i < N) ? deg[i] : 0;
    s[tid] = v;
    __syncthreads();
    for (int ofs = 1; ofs < 256; ofs <<= 1) {
        int t = (tid >= ofs) ? s[tid - ofs] : 0;
        __syncthreads();
        s[tid] += t;
        __syncthreads();
    }
    int excl = (tid == 0) ? 0 : s[tid - 1];
    if (i <= N) off[i] = bsums[blockIdx.x] + excl;
}

__global__ void fill_kernel(const int* __restrict__ src, const int* __restrict__ dst,
                            const int* __restrict__ off, int* __restrict__ fill,
                            int* __restrict__ csr, int E) {
    int i = blockIdx.x * blockDim.x + threadIdx.x;
    if (i < E) {
        int d = dst[i];
        int p = atomicAdd(&fill[d], 1);
        csr[off[d] + p] = src[i];
    }
}

// xs[n,:] = bf16( dinv[n] * X[n,:] ).  One thread per 8 elements.
__global__ void scalex_kernel(const float* __restrict__ x, const float* __restrict__ dinv,
                              unsigned short* __restrict__ xs, int n8) {
    int i = blockIdx.x * blockDim.x + threadIdx.x;
    if (i < n8) {
        float dv = dinv[i >> 4];                 // 16 groups of 8 per 128-row
        float4 v0 = ((const float4*)x)[i * 2];
        float4 v1 = ((const float4*)x)[i * 2 + 1];
        short8 o;
        o[0] = (short)f2bf(v0.x * dv); o[1] = (short)f2bf(v0.y * dv);
        o[2] = (short)f2bf(v0.z * dv); o[3] = (short)f2bf(v0.w * dv);
        o[4] = (short)f2bf(v1.x * dv); o[5] = (short)f2bf(v1.y * dv);
        o[6] = (short)f2bf(v1.z * dv); o[7] = (short)f2bf(v1.w * dv);
        *(short8*)(xs + (size_t)i * 8) = o;
    }
}

// WT[n][k] = bf16( W[k][n] )  (transpose for k-contiguous B fragments)
__global__ void wt_kernel(const float* __restrict__ W, unsigned short* __restrict__ WT,
                          int K, int N) {
    int t = blockIdx.x * blockDim.x + threadIdx.x;
    if (t < K * N) {
        int n = t / K, k = t - n * K;
        WT[t] = f2bf(W[(size_t)k * N + n]);
    }
}

// Wave-per-node aggregation over 128-dim bf16 rows, fp32 accumulate.
// Wave = 4 edge-slots x 16 lanes; edge loop unrolled x2 (independent partial sums)
// -> 8 row-gathers in flight per wave. 4 nodes per 256-block.
// MODE 0: out_bf16[n] = bf16( dinv[n] * (self + sum) )
// MODE 1: out_f32[n]  = dinv[n] * (self + sum) + bias
template <int MODE>
__global__ __launch_bounds__(256) void agg_bf16(const unsigned short* __restrict__ hs,
                                                const int* __restrict__ off,
                                                const int* __restrict__ csr,
                                                const float* __restrict__ dinv,
                                                const float* __restrict__ bias,
                                                void* __restrict__ outp, int N) {
    const int wid = threadIdx.x >> 6;
    const int n = blockIdx.x * 4 + wid;
    if (n >= N) return;
    const int lane = threadIdx.x & 63;
    const int lane16 = lane & 15;
    const int slot = lane >> 4;   // 0..3

    float va[8], vb[8];
#pragma unroll
    for (int j = 0; j < 8; j++) { va[j] = 0.f; vb[j] = 0.f; }

    if (slot == 0) {  // self loop
        short8 s = *(const short8*)(hs + (size_t)n * 128 + lane16 * 8);
#pragma unroll
        for (int j = 0; j < 8; j++) va[j] = bf2f((unsigned short)s[j]);
    }

    const int e1 = off[n + 1];
    int e = off[n] + slot;
    for (; e + 4 < e1; e += 8) {
        int s0 = csr[e];
        int s1 = csr[e + 4];
        short8 v0 = *(const short8*)(hs + (size_t)s0 * 128 + lane16 * 8);
        short8 v1 = *(const short8*)(hs + (size_t)s1 * 128 + lane16 * 8);
#pragma unroll
        for (int j = 0; j < 8; j++) va[j] += bf2f((unsigned short)v0[j]);
#pragma unroll
        for (int j = 0; j < 8; j++) vb[j] += bf2f((unsigned short)v1[j]);
    }
    if (e < e1) {
        int s0 = csr[e];
        short8 v0 = *(const short8*)(hs + (size_t)s0 * 128 + lane16 * 8);
#pragma unroll
        for (int j = 0; j < 8; j++) va[j] += bf2f((unsigned short)v0[j]);
    }
#pragma unroll
    for (int j = 0; j < 8; j++) va[j] += vb[j];

#pragma unroll
    for (int j = 0; j < 8; j++) va[j] += __shfl_down(va[j], 32);
#pragma unroll
    for (int j = 0; j < 8; j++) va[j] += __shfl_down(va[j], 16);

    if (lane < 16) {
        float dv = dinv[n];
        if (MODE == 0) {
            short8 o;
#pragma unroll
            for (int j = 0; j < 8; j++) o[j] = (short)f2bf(va[j] * dv);
            *(short8*)((unsigned short*)outp + (size_t)n * 128 + lane * 8) = o;
        } else {
            float* op = (float*)outp + (size_t)n * 128 + lane * 8;
            float4 o0, o1;
            o0.x = va[0] * dv + bias[lane * 8 + 0];
            o0.y = va[1] * dv + bias[lane * 8 + 1];
            o0.z = va[2] * dv + bias[lane * 8 + 2];
            o0.w = va[3] * dv + bias[lane * 8 + 3];
            o1.x = va[4] * dv + bias[lane * 8 + 4];
            o1.y = va[5] * dv + bias[lane * 8 + 5];
            o1.z = va[6] * dv + bias[lane * 8 + 6];
            o1.w = va[7] * dv + bias[lane * 8 + 7];
            ((float4*)op)[0] = o0;
            ((float4*)op)[1] = o1;
        }
    }
}

// bf16 MFMA GEMM, LDS-free.  Block = 4 waves = 2 row-groups x 2 col-groups.
// Wave = 32 rows (R=2 tiles, 2 indep accumulator chains) x NC/2 cols.
// B frags streamed from global WT (L2-resident); tile loop partially unrolled so
// the next tiles' B loads issue while current MFMAs run.
// A/B frag: m(or n)=lane&15, k=(lane>>4)*8+j.  D: col=lane&15, row=(lane>>4)*4+reg.
// EPI 1: relu(v + bias[col]) -> bf16.  EPI 0: v * dinv[m] -> bf16.
template <int K, int NC, int EPI>
__global__ __launch_bounds__(256) void mfma_gemm(const unsigned short* __restrict__ X,
                                                 const unsigned short* __restrict__ WT,
                                                 const float* __restrict__ bias,
                                                 const float* __restrict__ dinv,
                                                 unsigned short* __restrict__ out, int M) {
    constexpr int KC = K / 32;
    constexpr int TILES = NC / 32;        // 16-wide col tiles per wave (half of NC)
    const int wid = threadIdx.x >> 6;
    const int lane = threadIdx.x & 63;
    const int an = lane & 15;
    const int q = lane >> 4;
    const int rowgrp = wid & 1;
    const int colgrp = wid >> 1;
    const int m0 = blockIdx.x * 64 + rowgrp * 32;
    const int ntbase = colgrp * TILES;

    // A frags for 2 row tiles (clamped; stores are guarded)
    short8 a[2][KC];
#pragma unroll
    for (int r = 0; r < 2; r++) {
        int row = m0 + r * 16 + an;
        if (row >= M) row = M - 1;
        const unsigned short* xp = X + (size_t)row * K + q * 8;
#pragma unroll
        for (int c = 0; c < KC; c++) a[r][c] = *(const short8*)(xp + c * 32);
    }

    auto do_tile = [&](int t) {
        const int col = (ntbase + t) * 16 + an;
        const unsigned short* wp = WT + (size_t)col * K + q * 8;
        short8 b[KC];
#pragma unroll
        for (int c = 0; c < KC; c++) b[c] = *(const short8*)(wp + c * 32);
        f32x4 acc0 = {0.f, 0.f, 0.f, 0.f};
        f32x4 acc1 = {0.f, 0.f, 0.f, 0.f};
#pragma unroll
        for (int c = 0; c < KC; c++) {
            acc0 = __builtin_amdgcn_mfma_f32_16x16x32_bf16(a[0][c], b[c], acc0, 0, 0, 0);
            acc1 = __builtin_amdgcn_mfma_f32_16x16x32_bf16(a[1][c], b[c], acc1, 0, 0, 0);
        }
        float bv = (EPI == 1) ? bias[col] : 0.f;
#pragma unroll
        for (int rr = 0; rr < 4; rr++) {
            int m = m0 + q * 4 + rr;
            if (m < M) {
                float v = acc0[rr];
                if (EPI == 1) v = fmaxf(v + bv, 0.f);
                else v *= dinv[m];
                out[(size_t)m * NC + col] = f2bf(v);
            }
            int m2 = m0 + 16 + q * 4 + rr;
            if (m2 < M) {
                float v = acc1[rr];
                if (EPI == 1) v = fmaxf(v + bv, 0.f);
                else v *= dinv[m2];
                out[(size_t)m2 * NC + col] = f2bf(v);
            }
        }
    };

    if constexpr (K == 128) {
#pragma unroll 4
        for (int t = 0; t < TILES; t++) do_tile(t);
    } else {
#pragma unroll 2
        for (int t = 0; t < TILES; t++) do_tile(t);
    }
}

extern "C" void kernel_launch(void* const* d_in, const int* in_sizes, int n_in,
                              void* d_out, int out_size, void* d_ws, size_t ws_size,
                              hipStream_t stream) {
    const float* x  = (const float*)d_in[0];
    const int*   ei = (const int*)d_in[1];   // [2,E] int32
    const float* W1 = (const float*)d_in[2];
    const float* b1 = (const float*)d_in[3];
    const float* W2 = (const float*)d_in[4];
    const float* b2 = (const float*)d_in[5];

    const int N = N_NODES;
    const int E = N_EDGES;
    const int* srcp = ei;
    const int* dstp = ei + E;

    char* base = (char*)d_ws;
    size_t o = 0;
    auto alloc = [&](size_t bytes) {
        void* p = base + o;
        o = (o + bytes + 255) & ~(size_t)255;
        return p;
    };
    int*            deg  = (int*)alloc((size_t)N * 4);
    int*            offs = (int*)alloc((size_t)(N + 1) * 4);
    int*            fill = (int*)alloc((size_t)N * 4);
    float*          dinv = (float*)alloc((size_t)N * 4);
    int*            bsum = (int*)alloc(256 * 4);
    int*            csr  = (int*)alloc((size_t)E * 4);
    unsigned short* xs   = (unsigned short*)alloc((size_t)N * F_IN * 2);  // dinv*x, bf16
    unsigned short* Y    = (unsigned short*)alloc((size_t)N * F_IN * 2);  // A_hat@X, bf16
    unsigned short* h2   = (unsigned short*)alloc((size_t)N * HID * 2);   // relu(Y@W1+b1)
    unsigned short* w1t  = (unsigned short*)alloc((size_t)F_IN * HID * 2);
    unsigned short* w2t  = (unsigned short*)alloc((size_t)HID * F_OUT * 2);
    unsigned short* hs2  = xs;  // xs dead after agg1

    hipMemsetAsync(deg, 0, (size_t)N * 4, stream);
    hipMemsetAsync(fill, 0, (size_t)N * 4, stream);

    const int NB = (N + 256) / 256;   // covers i==N in scan_final
    deg_kernel<<<(E + 255) / 256, 256, 0, stream>>>(dstp, deg, E);
    dinv_kernel<<<(N + 255) / 256, 256, 0, stream>>>(deg, dinv, N);
    scan_reduce<<<NB, 256, 0, stream>>>(deg, bsum, N);
    scan_bsums<<<1, 256, 0, stream>>>(bsum, NB);
    scan_final<<<NB, 256, 0, stream>>>(deg, bsum, offs, N);
    fill_kernel<<<(E + 255) / 256, 256, 0, stream>>>(srcp, dstp, offs, fill, csr, E);
    scalex_kernel<<<(N * F_IN / 8 + 255) / 256, 256, 0, stream>>>(x, dinv, xs, N * F_IN / 8);
    wt_kernel<<<(F_IN * HID + 255) / 256, 256, 0, stream>>>(W1, w1t, F_IN, HID);
    wt_kernel<<<(HID * F_OUT + 255) / 256, 256, 0, stream>>>(W2, w2t, HID, F_OUT);

    // layer 1: Y = A_hat@X (bf16 gather); h2 = relu(Y@W1 + b1)
    agg_bf16<0><<<(N + 3) / 4, 256, 0, stream>>>(xs, offs, csr, dinv, nullptr, Y, N);
    mfma_gemm<F_IN, HID, 1><<<(N + 63) / 64, 256, 0, stream>>>(Y, w1t, b1, nullptr, h2, N);

    // layer 2: hs2 = dinv*(h2@W2); out = dinv*(hs2[self]+gather) + b2
    mfma_gemm<HID, F_OUT, 0><<<(N + 63) / 64, 256, 0, stream>>>(h2, w2t, nullptr, dinv, hs2, N);
    agg_bf16<1><<<(N + 3) / 4, 256, 0, stream>>>(hs2, offs, csr, dinv, b2, d_out, N);
}

// Round 6
// 280.139 us; speedup vs baseline: 2.2597x; 1.0579x over previous
//
#include <hip/hip_runtime.h>
#include <hip/hip_bf16.h>

// 2-layer GCN: out = A_hat @ relu((A_hat@X)@W1 + b1) @ W2 + b2,  A_hat = D^-1/2 (A+I) D^-1/2
// R6: (a) deg pass stores each edge's CSR slot (atomicAdd return) -> fill becomes a
//     pure scatter (no atomics, no fill[] array); (b) agg edge loop unrolled x4
//     (16 row-gathers in flight per wave). bf16 activations, fp32 accumulation.

static constexpr int N_NODES = 50000;
static constexpr int N_EDGES = 800000;
static constexpr int F_IN = 128;
static constexpr int HID  = 256;
static constexpr int F_OUT = 128;

typedef __attribute__((ext_vector_type(8))) short short8;   // 8 bf16 raw bits (4 VGPRs)
typedef __attribute__((ext_vector_type(4))) float f32x4;

__device__ __forceinline__ unsigned short f2bf(float f) {   // RNE fp32->bf16
    union { float f; unsigned u; } x; x.f = f;
    unsigned r = x.u + 0x7FFF + ((x.u >> 16) & 1);
    return (unsigned short)(r >> 16);
}
__device__ __forceinline__ float bf2f(unsigned short h) {
    union { unsigned u; float f; } x; x.u = ((unsigned)h) << 16;
    return x.f;
}

// pos[i] = slot of edge i within its dst bucket (atomicAdd return); deg[d] = count.
__global__ void deg_pos_kernel(const int* __restrict__ dst, int* __restrict__ deg,
                               int* __restrict__ pos, int E) {
    int i = blockIdx.x * blockDim.x + threadIdx.x;
    if (i < E) pos[i] = atomicAdd(&deg[dst[i]], 1);
}

__global__ void dinv_kernel(const int* __restrict__ deg, float* __restrict__ dinv, int N) {
    int i = blockIdx.x * blockDim.x + threadIdx.x;
    if (i < N) dinv[i] = rsqrtf((float)(deg[i] + 1));  // +1 = self loop
}

// ---- 3-phase exclusive scan of deg -> off (off[N] = E) ----
__global__ __launch_bounds__(256) void scan_reduce(const int* __restrict__ deg,
                                                   int* __restrict__ bsums, int N) {
    int i = blockIdx.x * 256 + threadIdx.x;
    int v = (i < N) ? deg[i] : 0;
#pragma unroll
    for (int ofs = 32; ofs > 0; ofs >>= 1) v += __shfl_down(v, ofs);
    __shared__ int ws[4];
    if ((threadIdx.x & 63) == 0) ws[threadIdx.x >> 6] = v;
    __syncthreads();
    if (threadIdx.x == 0) bsums[blockIdx.x] = ws[0] + ws[1] + ws[2] + ws[3];
}

__global__ __launch_bounds__(256) void scan_bsums(int* __restrict__ bsums, int nb) {
    __shared__ int s[256];
    int tid = threadIdx.x;
    s[tid] = (tid < nb) ? bsums[tid] : 0;
    __syncthreads();
    for (int ofs = 1; ofs < 256; ofs <<= 1) {
        int v = (tid >= ofs) ? s[tid - ofs] : 0;
        __syncthreads();
        s[tid] += v;
        __syncthreads();
    }
    bsums[tid] = (tid == 0) ? 0 : s[tid - 1];   // exclusive
}

__global__ __launch_bounds__(256) void scan_final(const int* __restrict__ deg,
                                                  const int* __restrict__ bsums,
                                                  int* __restrict__ off, int N) {
    __shared__ int s[256];
    const int tid = threadIdx.x;
    const int i = blockIdx.x * 256 + tid;
    int v = (i < N) ? deg[i] : 0;
    s[tid] = v;
    __syncthreads();
    for (int ofs = 1; ofs < 256; ofs <<= 1) {
        int t = (tid >= ofs) ? s[tid - ofs] : 0;
        __syncthreads();
        s[tid] += t;
        __syncthreads();
    }
    int excl = (tid == 0) ? 0 : s[tid - 1];
    if (i <= N) off[i] = bsums[blockIdx.x] + excl;
}

// Pure scatter: csr[off[dst] + pos] = src.  No atomics.
__global__ void scatter_kernel(const int* __restrict__ src, const int* __restrict__ dst,
                               const int* __restrict__ pos, const int* __restrict__ off,
                               int* __restrict__ csr, int E) {
    int i = blockIdx.x * blockDim.x + threadIdx.x;
    if (i < E) csr[off[dst[i]] + pos[i]] = src[i];
}

// xs[n,:] = bf16( dinv[n] * X[n,:] ).  One thread per 8 elements.
__global__ void scalex_kernel(const float* __restrict__ x, const float* __restrict__ dinv,
                              unsigned short* __restrict__ xs, int n8) {
    int i = blockIdx.x * blockDim.x + threadIdx.x;
    if (i < n8) {
        float dv = dinv[i >> 4];                 // 16 groups of 8 per 128-row
        float4 v0 = ((const float4*)x)[i * 2];
        float4 v1 = ((const float4*)x)[i * 2 + 1];
        short8 o;
        o[0] = (short)f2bf(v0.x * dv); o[1] = (short)f2bf(v0.y * dv);
        o[2] = (short)f2bf(v0.z * dv); o[3] = (short)f2bf(v0.w * dv);
        o[4] = (short)f2bf(v1.x * dv); o[5] = (short)f2bf(v1.y * dv);
        o[6] = (short)f2bf(v1.z * dv); o[7] = (short)f2bf(v1.w * dv);
        *(short8*)(xs + (size_t)i * 8) = o;
    }
}

// WT[n][k] = bf16( W[k][n] )  (transpose for k-contiguous B fragments)
__global__ void wt_kernel(const float* __restrict__ W, unsigned short* __restrict__ WT,
                          int K, int N) {
    int t = blockIdx.x * blockDim.x + threadIdx.x;
    if (t < K * N) {
        int n = t / K, k = t - n * K;
        WT[t] = f2bf(W[(size_t)k * N + n]);
    }
}

// Wave-per-node aggregation over 128-dim bf16 rows, fp32 accumulate.
// Wave = 4 edge-slots x 16 lanes; edge loop unrolled x4 (4 independent partial sums)
// -> up to 16 row-gathers in flight per wave. 4 nodes per 256-block.
// MODE 0: out_bf16[n] = bf16( dinv[n] * (self + sum) )
// MODE 1: out_f32[n]  = dinv[n] * (self + sum) + bias
template <int MODE>
__global__ __launch_bounds__(256) void agg_bf16(const unsigned short* __restrict__ hs,
                                                const int* __restrict__ off,
                                                const int* __restrict__ csr,
                                                const float* __restrict__ dinv,
                                                const float* __restrict__ bias,
                                                void* __restrict__ outp, int N) {
    const int wid = threadIdx.x >> 6;
    const int n = blockIdx.x * 4 + wid;
    if (n >= N) return;
    const int lane = threadIdx.x & 63;
    const int lane16 = lane & 15;
    const int slot = lane >> 4;   // 0..3

    float va[8], vb[8], vc[8], vd[8];
#pragma unroll
    for (int j = 0; j < 8; j++) { va[j] = 0.f; vb[j] = 0.f; vc[j] = 0.f; vd[j] = 0.f; }

    if (slot == 0) {  // self loop
        short8 s = *(const short8*)(hs + (size_t)n * 128 + lane16 * 8);
#pragma unroll
        for (int j = 0; j < 8; j++) va[j] = bf2f((unsigned short)s[j]);
    }

    const int e1 = off[n + 1];
    int e = off[n] + slot;
    for (; e + 12 < e1; e += 16) {
        int s0 = csr[e];
        int s1 = csr[e + 4];
        int s2 = csr[e + 8];
        int s3 = csr[e + 12];
        short8 v0 = *(const short8*)(hs + (size_t)s0 * 128 + lane16 * 8);
        short8 v1 = *(const short8*)(hs + (size_t)s1 * 128 + lane16 * 8);
        short8 v2 = *(const short8*)(hs + (size_t)s2 * 128 + lane16 * 8);
        short8 v3 = *(const short8*)(hs + (size_t)s3 * 128 + lane16 * 8);
#pragma unroll
        for (int j = 0; j < 8; j++) va[j] += bf2f((unsigned short)v0[j]);
#pragma unroll
        for (int j = 0; j < 8; j++) vb[j] += bf2f((unsigned short)v1[j]);
#pragma unroll
        for (int j = 0; j < 8; j++) vc[j] += bf2f((unsigned short)v2[j]);
#pragma unroll
        for (int j = 0; j < 8; j++) vd[j] += bf2f((unsigned short)v3[j]);
    }
    for (; e < e1; e += 4) {
        int s0 = csr[e];
        short8 v0 = *(const short8*)(hs + (size_t)s0 * 128 + lane16 * 8);
#pragma unroll
        for (int j = 0; j < 8; j++) va[j] += bf2f((unsigned short)v0[j]);
    }
#pragma unroll
    for (int j = 0; j < 8; j++) va[j] += vb[j] + vc[j] + vd[j];

#pragma unroll
    for (int j = 0; j < 8; j++) va[j] += __shfl_down(va[j], 32);
#pragma unroll
    for (int j = 0; j < 8; j++) va[j] += __shfl_down(va[j], 16);

    if (lane < 16) {
        float dv = dinv[n];
        if (MODE == 0) {
            short8 o;
#pragma unroll
            for (int j = 0; j < 8; j++) o[j] = (short)f2bf(va[j] * dv);
            *(short8*)((unsigned short*)outp + (size_t)n * 128 + lane * 8) = o;
        } else {
            float* op = (float*)outp + (size_t)n * 128 + lane * 8;
            float4 o0, o1;
            o0.x = va[0] * dv + bias[lane * 8 + 0];
            o0.y = va[1] * dv + bias[lane * 8 + 1];
            o0.z = va[2] * dv + bias[lane * 8 + 2];
            o0.w = va[3] * dv + bias[lane * 8 + 3];
            o1.x = va[4] * dv + bias[lane * 8 + 4];
            o1.y = va[5] * dv + bias[lane * 8 + 5];
            o1.z = va[6] * dv + bias[lane * 8 + 6];
            o1.w = va[7] * dv + bias[lane * 8 + 7];
            ((float4*)op)[0] = o0;
            ((float4*)op)[1] = o1;
        }
    }
}

// bf16 MFMA GEMM, LDS-free.  Block = 4 waves = 2 row-groups x 2 col-groups.
// Wave = 32 rows (R=2 tiles, 2 indep accumulator chains) x NC/2 cols.
// B frags streamed from global WT (L2-resident); tile loop partially unrolled so
// the next tiles' B loads issue while current MFMAs run.
// A/B frag: m(or n)=lane&15, k=(lane>>4)*8+j.  D: col=lane&15, row=(lane>>4)*4+reg.
// EPI 1: relu(v + bias[col]) -> bf16.  EPI 0: v * dinv[m] -> bf16.
template <int K, int NC, int EPI>
__global__ __launch_bounds__(256) void mfma_gemm(const unsigned short* __restrict__ X,
                                                 const unsigned short* __restrict__ WT,
                                                 const float* __restrict__ bias,
                                                 const float* __restrict__ dinv,
                                                 unsigned short* __restrict__ out, int M) {
    constexpr int KC = K / 32;
    constexpr int TILES = NC / 32;        // 16-wide col tiles per wave (half of NC)
    const int wid = threadIdx.x >> 6;
    const int lane = threadIdx.x & 63;
    const int an = lane & 15;
    const int q = lane >> 4;
    const int rowgrp = wid & 1;
    const int colgrp = wid >> 1;
    const int m0 = blockIdx.x * 64 + rowgrp * 32;
    const int ntbase = colgrp * TILES;

    // A frags for 2 row tiles (clamped; stores are guarded)
    short8 a[2][KC];
#pragma unroll
    for (int r = 0; r < 2; r++) {
        int row = m0 + r * 16 + an;
        if (row >= M) row = M - 1;
        const unsigned short* xp = X + (size_t)row * K + q * 8;
#pragma unroll
        for (int c = 0; c < KC; c++) a[r][c] = *(const short8*)(xp + c * 32);
    }

    auto do_tile = [&](int t) {
        const int col = (ntbase + t) * 16 + an;
        const unsigned short* wp = WT + (size_t)col * K + q * 8;
        short8 b[KC];
#pragma unroll
        for (int c = 0; c < KC; c++) b[c] = *(const short8*)(wp + c * 32);
        f32x4 acc0 = {0.f, 0.f, 0.f, 0.f};
        f32x4 acc1 = {0.f, 0.f, 0.f, 0.f};
#pragma unroll
        for (int c = 0; c < KC; c++) {
            acc0 = __builtin_amdgcn_mfma_f32_16x16x32_bf16(a[0][c], b[c], acc0, 0, 0, 0);
            acc1 = __builtin_amdgcn_mfma_f32_16x16x32_bf16(a[1][c], b[c], acc1, 0, 0, 0);
        }
        float bv = (EPI == 1) ? bias[col] : 0.f;
#pragma unroll
        for (int rr = 0; rr < 4; rr++) {
            int m = m0 + q * 4 + rr;
            if (m < M) {
                float v = acc0[rr];
                if (EPI == 1) v = fmaxf(v + bv, 0.f);
                else v *= dinv[m];
                out[(size_t)m * NC + col] = f2bf(v);
            }
            int m2 = m0 + 16 + q * 4 + rr;
            if (m2 < M) {
                float v = acc1[rr];
                if (EPI == 1) v = fmaxf(v + bv, 0.f);
                else v *= dinv[m2];
                out[(size_t)m2 * NC + col] = f2bf(v);
            }
        }
    };

    if constexpr (K == 128) {
#pragma unroll 4
        for (int t = 0; t < TILES; t++) do_tile(t);
    } else {
#pragma unroll 2
        for (int t = 0; t < TILES; t++) do_tile(t);
    }
}

extern "C" void kernel_launch(void* const* d_in, const int* in_sizes, int n_in,
                              void* d_out, int out_size, void* d_ws, size_t ws_size,
                              hipStream_t stream) {
    const float* x  = (const float*)d_in[0];
    const int*   ei = (const int*)d_in[1];   // [2,E] int32
    const float* W1 = (const float*)d_in[2];
    const float* b1 = (const float*)d_in[3];
    const float* W2 = (const float*)d_in[4];
    const float* b2 = (const float*)d_in[5];

    const int N = N_NODES;
    const int E = N_EDGES;
    const int* srcp = ei;
    const int* dstp = ei + E;

    char* base = (char*)d_ws;
    size_t o = 0;
    auto alloc = [&](size_t bytes) {
        void* p = base + o;
        o = (o + bytes + 255) & ~(size_t)255;
        return p;
    };
    int*            deg  = (int*)alloc((size_t)N * 4);
    int*            offs = (int*)alloc((size_t)(N + 1) * 4);
    float*          dinv = (float*)alloc((size_t)N * 4);
    int*            bsum = (int*)alloc(256 * 4);
    int*            pos  = (int*)alloc((size_t)E * 4);
    int*            csr  = (int*)alloc((size_t)E * 4);
    unsigned short* xs   = (unsigned short*)alloc((size_t)N * F_IN * 2);  // dinv*x, bf16
    unsigned short* Y    = (unsigned short*)alloc((size_t)N * F_IN * 2);  // A_hat@X, bf16
    unsigned short* h2   = (unsigned short*)alloc((size_t)N * HID * 2);   // relu(Y@W1+b1)
    unsigned short* w1t  = (unsigned short*)alloc((size_t)F_IN * HID * 2);
    unsigned short* w2t  = (unsigned short*)alloc((size_t)HID * F_OUT * 2);
    unsigned short* hs2  = xs;  // xs dead after agg1

    hipMemsetAsync(deg, 0, (size_t)N * 4, stream);

    const int NB = (N + 256) / 256;   // covers i==N in scan_final
    deg_pos_kernel<<<(E + 255) / 256, 256, 0, stream>>>(dstp, deg, pos, E);
    dinv_kernel<<<(N + 255) / 256, 256, 0, stream>>>(deg, dinv, N);
    scan_reduce<<<NB, 256, 0, stream>>>(deg, bsum, N);
    scan_bsums<<<1, 256, 0, stream>>>(bsum, NB);
    scan_final<<<NB, 256, 0, stream>>>(deg, bsum, offs, N);
    scatter_kernel<<<(E + 255) / 256, 256, 0, stream>>>(srcp, dstp, pos, offs, csr, E);
    scalex_kernel<<<(N * F_IN / 8 + 255) / 256, 256, 0, stream>>>(x, dinv, xs, N * F_IN / 8);
    wt_kernel<<<(F_IN * HID + 255) / 256, 256, 0, stream>>>(W1, w1t, F_IN, HID);
    wt_kernel<<<(HID * F_OUT + 255) / 256, 256, 0, stream>>>(W2, w2t, HID, F_OUT);

    // layer 1: Y = A_hat@X (bf16 gather); h2 = relu(Y@W1 + b1)
    agg_bf16<0><<<(N + 3) / 4, 256, 0, stream>>>(xs, offs, csr, dinv, nullptr, Y, N);
    mfma_gemm<F_IN, HID, 1><<<(N + 63) / 64, 256, 0, stream>>>(Y, w1t, b1, nullptr, h2, N);

    // layer 2: hs2 = dinv*(h2@W2); out = dinv*(hs2[self]+gather) + b2
    mfma_gemm<HID, F_OUT, 0><<<(N + 63) / 64, 256, 0, stream>>>(h2, w2t, nullptr, dinv, hs2, N);
    agg_bf16<1><<<(N + 3) / 4, 256, 0, stream>>>(hs2, offs, csr, dinv, b2, d_out, N);
}

// Round 7
// 263.614 us; speedup vs baseline: 2.4013x; 1.0627x over previous
//
#include <hip/hip_runtime.h>
#include <hip/hip_bf16.h>

// 2-layer GCN: out = A_hat @ relu((A_hat@X)@W1 + b1) @ W2 + b2,  A_hat = D^-1/2 (A+I) D^-1/2
// R7: (a) agg uses predicated-batch gather loop (all 16 row loads per wave-batch in
//     flight; no serial remainder tail -- avg degree ~16 means the tail was ~half the
//     work); (b) kernel fusion 14 -> 10 dispatches (dinv+scan_reduce; bsums-scan folded
//     into scan_final; scalex+wt1+wt2 -> one prep kernel).
// bf16 activations/gathers, fp32 accumulation everywhere.

static constexpr int N_NODES = 50000;
static constexpr int N_EDGES = 800000;
static constexpr int F_IN = 128;
static constexpr int HID  = 256;
static constexpr int F_OUT = 128;

typedef __attribute__((ext_vector_type(8))) short short8;   // 8 bf16 raw bits (4 VGPRs)
typedef __attribute__((ext_vector_type(4))) float f32x4;

__device__ __forceinline__ unsigned short f2bf(float f) {   // RNE fp32->bf16
    union { float f; unsigned u; } x; x.f = f;
    unsigned r = x.u + 0x7FFF + ((x.u >> 16) & 1);
    return (unsigned short)(r >> 16);
}
__device__ __forceinline__ float bf2f(unsigned short h) {
    union { unsigned u; float f; } x; x.u = ((unsigned)h) << 16;
    return x.f;
}

// pos[i] = slot of edge i within its dst bucket (atomicAdd return); deg[d] = count.
__global__ void deg_pos_kernel(const int* __restrict__ dst, int* __restrict__ deg,
                               int* __restrict__ pos, int E) {
    int i = blockIdx.x * blockDim.x + threadIdx.x;
    if (i < E) pos[i] = atomicAdd(&deg[dst[i]], 1);
}

// Fused: per-block sum of deg -> bsums, plus dinv[i] = rsqrt(deg+1).
__global__ __launch_bounds__(256) void scan_reduce_dinv(const int* __restrict__ deg,
                                                        int* __restrict__ bsums,
                                                        float* __restrict__ dinv, int N) {
    int i = blockIdx.x * 256 + threadIdx.x;
    int v = (i < N) ? deg[i] : 0;
    if (i < N) dinv[i] = rsqrtf((float)(v + 1));   // +1 = self loop
#pragma unroll
    for (int ofs = 32; ofs > 0; ofs >>= 1) v += __shfl_down(v, ofs);
    __shared__ int ws[4];
    if ((threadIdx.x & 63) == 0) ws[threadIdx.x >> 6] = v;
    __syncthreads();
    if (threadIdx.x == 0) bsums[blockIdx.x] = ws[0] + ws[1] + ws[2] + ws[3];
}

// Fused: every block redundantly scans bsums (<=256 entries) in LDS, then does its
// intra-block exclusive scan of deg -> off.  off[N] = E.
__global__ __launch_bounds__(256) void scan_final(const int* __restrict__ deg,
                                                  const int* __restrict__ bsums,
                                                  int* __restrict__ off, int N, int nb) {
    __shared__ int bs[256];
    __shared__ int s[256];
    const int tid = threadIdx.x;
    bs[tid] = (tid < nb) ? bsums[tid] : 0;
    const int i = blockIdx.x * 256 + tid;
    int v = (i < N) ? deg[i] : 0;
    s[tid] = v;
    __syncthreads();
    for (int ofs = 1; ofs < 256; ofs <<= 1) {
        int tb = (tid >= ofs) ? bs[tid - ofs] : 0;
        int tv = (tid >= ofs) ? s[tid - ofs] : 0;
        __syncthreads();
        bs[tid] += tb;
        s[tid] += tv;
        __syncthreads();
    }
    int bbase = (blockIdx.x == 0) ? 0 : bs[blockIdx.x - 1];
    int excl = (tid == 0) ? 0 : s[tid - 1];
    if (i <= N) off[i] = bbase + excl;
}

// Pure scatter: csr[off[dst] + pos] = src.  No atomics.
__global__ void scatter_kernel(const int* __restrict__ src, const int* __restrict__ dst,
                               const int* __restrict__ pos, const int* __restrict__ off,
                               int* __restrict__ csr, int E) {
    int i = blockIdx.x * blockDim.x + threadIdx.x;
    if (i < E) csr[off[dst[i]] + pos[i]] = src[i];
}

// Fused prep: [0, NBX) blocks: xs = bf16(dinv*x); then wt1; then wt2.
__global__ void prep_kernel(const float* __restrict__ x, const float* __restrict__ dinv,
                            unsigned short* __restrict__ xs,
                            const float* __restrict__ W1, unsigned short* __restrict__ w1t,
                            const float* __restrict__ W2, unsigned short* __restrict__ w2t,
                            int NBX, int NB1) {
    const int b = blockIdx.x;
    if (b < NBX) {
        int i = b * 256 + threadIdx.x;               // one thread per 8 elems
        if (i < N_NODES * F_IN / 8) {
            float dv = dinv[i >> 4];
            float4 v0 = ((const float4*)x)[i * 2];
            float4 v1 = ((const float4*)x)[i * 2 + 1];
            short8 o;
            o[0] = (short)f2bf(v0.x * dv); o[1] = (short)f2bf(v0.y * dv);
            o[2] = (short)f2bf(v0.z * dv); o[3] = (short)f2bf(v0.w * dv);
            o[4] = (short)f2bf(v1.x * dv); o[5] = (short)f2bf(v1.y * dv);
            o[6] = (short)f2bf(v1.z * dv); o[7] = (short)f2bf(v1.w * dv);
            *(short8*)(xs + (size_t)i * 8) = o;
        }
    } else if (b < NBX + NB1) {
        int t = (b - NBX) * 256 + threadIdx.x;       // W1: K=F_IN rows, HID cols
        if (t < F_IN * HID) {
            int n = t / F_IN, k = t - n * F_IN;
            w1t[t] = f2bf(W1[(size_t)k * HID + n]);
        }
    } else {
        int t = (b - NBX - NB1) * 256 + threadIdx.x; // W2: K=HID rows, F_OUT cols
        if (t < HID * F_OUT) {
            int n = t / HID, k = t - n * HID;
            w2t[t] = f2bf(W2[(size_t)k * F_OUT + n]);
        }
    }
}

// Wave-per-node aggregation over 128-dim bf16 rows, fp32 accumulate.
// Wave = 4 edge-slots x 16 lanes (ushort8 / 16 B per lane); 4 nodes per 256-block.
// Predicated-batch loop: each batch issues 4 clamped loads per slot (16 per wave),
// invalid lanes masked via fmaf(flag,...). No serial remainder.
// MODE 0: out_bf16[n] = bf16( dinv[n] * (self + sum) )
// MODE 1: out_f32[n]  = dinv[n] * (self + sum) + bias
template <int MODE>
__global__ __launch_bounds__(256) void agg_bf16(const unsigned short* __restrict__ hs,
                                                const int* __restrict__ off,
                                                const int* __restrict__ csr,
                                                const float* __restrict__ dinv,
                                                const float* __restrict__ bias,
                                                void* __restrict__ outp, int N) {
    const int wid = threadIdx.x >> 6;
    const int n = blockIdx.x * 4 + wid;
    if (n >= N) return;
    const int lane = threadIdx.x & 63;
    const int lane16 = lane & 15;
    const int slot = lane >> 4;   // 0..3

    float va[8], vb[8], vc[8], vd[8];
#pragma unroll
    for (int j = 0; j < 8; j++) { va[j] = 0.f; vb[j] = 0.f; vc[j] = 0.f; vd[j] = 0.f; }

    if (slot == 0) {  // self loop
        short8 s = *(const short8*)(hs + (size_t)n * 128 + lane16 * 8);
#pragma unroll
        for (int j = 0; j < 8; j++) va[j] = bf2f((unsigned short)s[j]);
    }

    const int e0 = off[n];
    const int e1 = off[n + 1];
    for (int e = e0 + slot; e < e1; e += 16) {
        const int i1 = e + 4, i2 = e + 8, i3 = e + 12;
        const float f1 = (i1 < e1) ? 1.f : 0.f;
        const float f2 = (i2 < e1) ? 1.f : 0.f;
        const float f3 = (i3 < e1) ? 1.f : 0.f;
        const int c1 = min(i1, e1 - 1), c2 = min(i2, e1 - 1), c3 = min(i3, e1 - 1);
        int s0 = csr[e];
        int s1 = csr[c1];
        int s2 = csr[c2];
        int s3 = csr[c3];
        short8 v0 = *(const short8*)(hs + (size_t)s0 * 128 + lane16 * 8);
        short8 v1 = *(const short8*)(hs + (size_t)s1 * 128 + lane16 * 8);
        short8 v2 = *(const short8*)(hs + (size_t)s2 * 128 + lane16 * 8);
        short8 v3 = *(const short8*)(hs + (size_t)s3 * 128 + lane16 * 8);
#pragma unroll
        for (int j = 0; j < 8; j++) va[j] += bf2f((unsigned short)v0[j]);
#pragma unroll
        for (int j = 0; j < 8; j++) vb[j] = fmaf(f1, bf2f((unsigned short)v1[j]), vb[j]);
#pragma unroll
        for (int j = 0; j < 8; j++) vc[j] = fmaf(f2, bf2f((unsigned short)v2[j]), vc[j]);
#pragma unroll
        for (int j = 0; j < 8; j++) vd[j] = fmaf(f3, bf2f((unsigned short)v3[j]), vd[j]);
    }
#pragma unroll
    for (int j = 0; j < 8; j++) va[j] += vb[j] + vc[j] + vd[j];

#pragma unroll
    for (int j = 0; j < 8; j++) va[j] += __shfl_down(va[j], 32);
#pragma unroll
    for (int j = 0; j < 8; j++) va[j] += __shfl_down(va[j], 16);

    if (lane < 16) {
        float dv = dinv[n];
        if (MODE == 0) {
            short8 o;
#pragma unroll
            for (int j = 0; j < 8; j++) o[j] = (short)f2bf(va[j] * dv);
            *(short8*)((unsigned short*)outp + (size_t)n * 128 + lane * 8) = o;
        } else {
            float* op = (float*)outp + (size_t)n * 128 + lane * 8;
            float4 o0, o1;
            o0.x = va[0] * dv + bias[lane * 8 + 0];
            o0.y = va[1] * dv + bias[lane * 8 + 1];
            o0.z = va[2] * dv + bias[lane * 8 + 2];
            o0.w = va[3] * dv + bias[lane * 8 + 3];
            o1.x = va[4] * dv + bias[lane * 8 + 4];
            o1.y = va[5] * dv + bias[lane * 8 + 5];
            o1.z = va[6] * dv + bias[lane * 8 + 6];
            o1.w = va[7] * dv + bias[lane * 8 + 7];
            ((float4*)op)[0] = o0;
            ((float4*)op)[1] = o1;
        }
    }
}

// bf16 MFMA GEMM, LDS-free.  Block = 4 waves = 2 row-groups x 2 col-groups.
// Wave = 32 rows (R=2 tiles, 2 indep accumulator chains) x NC/2 cols.
// B frags streamed from global WT (L2-resident); tile loop partially unrolled so
// the next tiles' B loads issue while current MFMAs run.
// A/B frag: m(or n)=lane&15, k=(lane>>4)*8+j.  D: col=lane&15, row=(lane>>4)*4+reg.
// EPI 1: relu(v + bias[col]) -> bf16.  EPI 0: v * dinv[m] -> bf16.
template <int K, int NC, int EPI>
__global__ __launch_bounds__(256) void mfma_gemm(const unsigned short* __restrict__ X,
                                                 const unsigned short* __restrict__ WT,
                                                 const float* __restrict__ bias,
                                                 const float* __restrict__ dinv,
                                                 unsigned short* __restrict__ out, int M) {
    constexpr int KC = K / 32;
    constexpr int TILES = NC / 32;        // 16-wide col tiles per wave (half of NC)
    const int wid = threadIdx.x >> 6;
    const int lane = threadIdx.x & 63;
    const int an = lane & 15;
    const int q = lane >> 4;
    const int rowgrp = wid & 1;
    const int colgrp = wid >> 1;
    const int m0 = blockIdx.x * 64 + rowgrp * 32;
    const int ntbase = colgrp * TILES;

    // A frags for 2 row tiles (clamped; stores are guarded)
    short8 a[2][KC];
#pragma unroll
    for (int r = 0; r < 2; r++) {
        int row = m0 + r * 16 + an;
        if (row >= M) row = M - 1;
        const unsigned short* xp = X + (size_t)row * K + q * 8;
#pragma unroll
        for (int c = 0; c < KC; c++) a[r][c] = *(const short8*)(xp + c * 32);
    }

    auto do_tile = [&](int t) {
        const int col = (ntbase + t) * 16 + an;
        const unsigned short* wp = WT + (size_t)col * K + q * 8;
        short8 b[KC];
#pragma unroll
        for (int c = 0; c < KC; c++) b[c] = *(const short8*)(wp + c * 32);
        f32x4 acc0 = {0.f, 0.f, 0.f, 0.f};
        f32x4 acc1 = {0.f, 0.f, 0.f, 0.f};
#pragma unroll
        for (int c = 0; c < KC; c++) {
            acc0 = __builtin_amdgcn_mfma_f32_16x16x32_bf16(a[0][c], b[c], acc0, 0, 0, 0);
            acc1 = __builtin_amdgcn_mfma_f32_16x16x32_bf16(a[1][c], b[c], acc1, 0, 0, 0);
        }
        float bv = (EPI == 1) ? bias[col] : 0.f;
#pragma unroll
        for (int rr = 0; rr < 4; rr++) {
            int m = m0 + q * 4 + rr;
            if (m < M) {
                float v = acc0[rr];
                if (EPI == 1) v = fmaxf(v + bv, 0.f);
                else v *= dinv[m];
                out[(size_t)m * NC + col] = f2bf(v);
            }
            int m2 = m0 + 16 + q * 4 + rr;
            if (m2 < M) {
                float v = acc1[rr];
                if (EPI == 1) v = fmaxf(v + bv, 0.f);
                else v *= dinv[m2];
                out[(size_t)m2 * NC + col] = f2bf(v);
            }
        }
    };

    if constexpr (K == 128) {
#pragma unroll 4
        for (int t = 0; t < TILES; t++) do_tile(t);
    } else {
#pragma unroll 2
        for (int t = 0; t < TILES; t++) do_tile(t);
    }
}

extern "C" void kernel_launch(void* const* d_in, const int* in_sizes, int n_in,
                              void* d_out, int out_size, void* d_ws, size_t ws_size,
                              hipStream_t stream) {
    const float* x  = (const float*)d_in[0];
    const int*   ei = (const int*)d_in[1];   // [2,E] int32
    const float* W1 = (const float*)d_in[2];
    const float* b1 = (const float*)d_in[3];
    const float* W2 = (const float*)d_in[4];
    const float* b2 = (const float*)d_in[5];

    const int N = N_NODES;
    const int E = N_EDGES;
    const int* srcp = ei;
    const int* dstp = ei + E;

    char* base = (char*)d_ws;
    size_t o = 0;
    auto alloc = [&](size_t bytes) {
        void* p = base + o;
        o = (o + bytes + 255) & ~(size_t)255;
        return p;
    };
    int*            deg  = (int*)alloc((size_t)N * 4);
    int*            offs = (int*)alloc((size_t)(N + 1) * 4);
    float*          dinv = (float*)alloc((size_t)N * 4);
    int*            bsum = (int*)alloc(256 * 4);
    int*            pos  = (int*)alloc((size_t)E * 4);
    int*            csr  = (int*)alloc((size_t)E * 4);
    unsigned short* xs   = (unsigned short*)alloc((size_t)N * F_IN * 2);  // dinv*x, bf16
    unsigned short* Y    = (unsigned short*)alloc((size_t)N * F_IN * 2);  // A_hat@X, bf16
    unsigned short* h2   = (unsigned short*)alloc((size_t)N * HID * 2);   // relu(Y@W1+b1)
    unsigned short* w1t  = (unsigned short*)alloc((size_t)F_IN * HID * 2);
    unsigned short* w2t  = (unsigned short*)alloc((size_t)HID * F_OUT * 2);
    unsigned short* hs2  = xs;  // xs dead after agg1

    hipMemsetAsync(deg, 0, (size_t)N * 4, stream);

    const int NB = (N + 256) / 256;            // covers i==N in scan_final (196)
    const int NBX = (N * F_IN / 8 + 255) / 256;
    const int NB1 = (F_IN * HID + 255) / 256;
    const int NB2 = (HID * F_OUT + 255) / 256;

    deg_pos_kernel<<<(E + 255) / 256, 256, 0, stream>>>(dstp, deg, pos, E);
    scan_reduce_dinv<<<NB, 256, 0, stream>>>(deg, bsum, dinv, N);
    scan_final<<<NB, 256, 0, stream>>>(deg, bsum, offs, N, NB);
    scatter_kernel<<<(E + 255) / 256, 256, 0, stream>>>(srcp, dstp, pos, offs, csr, E);
    prep_kernel<<<NBX + NB1 + NB2, 256, 0, stream>>>(x, dinv, xs, W1, w1t, W2, w2t, NBX, NB1);

    // layer 1: Y = A_hat@X (bf16 gather); h2 = relu(Y@W1 + b1)
    agg_bf16<0><<<(N + 3) / 4, 256, 0, stream>>>(xs, offs, csr, dinv, nullptr, Y, N);
    mfma_gemm<F_IN, HID, 1><<<(N + 63) / 64, 256, 0, stream>>>(Y, w1t, b1, nullptr, h2, N);

    // layer 2: hs2 = dinv*(h2@W2); out = dinv*(hs2[self]+gather) + b2
    mfma_gemm<HID, F_OUT, 0><<<(N + 63) / 64, 256, 0, stream>>>(h2, w2t, nullptr, dinv, hs2, N);
    agg_bf16<1><<<(N + 3) / 4, 256, 0, stream>>>(hs2, offs, csr, dinv, b2, d_out, N);
}

// Round 8
// 251.643 us; speedup vs baseline: 2.5155x; 1.0476x over previous
//
#include <hip/hip_runtime.h>
#include <hip/hip_bf16.h>

// 2-layer GCN: out = A_hat @ relu((A_hat@X)@W1 + b1) @ W2 + b2,  A_hat = D^-1/2 (A+I) D^-1/2
// R8: (a) gemm1+gemm2 fused into one kernel -- h2 tile lives in LDS (64 x 264-pitch bf16,
//     +8 pad: lanes hit 2-way bank aliasing = free), killing the 51 MB h2 roundtrip and a
//     launch; (b) independent prep fused grid-partitioned: deg_pos+wt1+wt2, scan_final+scalex.
//     10 -> 8 dispatches. bf16 activations/gathers, fp32 accumulation everywhere.

static constexpr int N_NODES = 50000;
static constexpr int N_EDGES = 800000;
static constexpr int F_IN = 128;
static constexpr int HID  = 256;
static constexpr int F_OUT = 128;
static constexpr int H2P  = HID + 8;   // LDS pitch (shorts) for h2 tile

typedef __attribute__((ext_vector_type(8))) short short8;   // 8 bf16 raw bits (4 VGPRs)
typedef __attribute__((ext_vector_type(4))) float f32x4;

__device__ __forceinline__ unsigned short f2bf(float f) {   // RNE fp32->bf16
    union { float f; unsigned u; } x; x.f = f;
    unsigned r = x.u + 0x7FFF + ((x.u >> 16) & 1);
    return (unsigned short)(r >> 16);
}
__device__ __forceinline__ float bf2f(unsigned short h) {
    union { unsigned u; float f; } x; x.u = ((unsigned)h) << 16;
    return x.f;
}

// Fused independent prep: deg/pos atomics  |  W1^T  |  W2^T   (grid-partitioned)
__global__ void deg_wt_kernel(const int* __restrict__ dst, int* __restrict__ deg,
                              int* __restrict__ pos, int E,
                              const float* __restrict__ W1, unsigned short* __restrict__ w1t,
                              const float* __restrict__ W2, unsigned short* __restrict__ w2t,
                              int EB, int NB1) {
    const int b = blockIdx.x;
    if (b < EB) {
        int i = b * 256 + threadIdx.x;
        if (i < E) pos[i] = atomicAdd(&deg[dst[i]], 1);
    } else if (b < EB + NB1) {
        int t = (b - EB) * 256 + threadIdx.x;       // W1: F_IN rows x HID cols -> w1t[HID][F_IN]
        if (t < F_IN * HID) {
            int n = t / F_IN, k = t - n * F_IN;
            w1t[t] = f2bf(W1[(size_t)k * HID + n]);
        }
    } else {
        int t = (b - EB - NB1) * 256 + threadIdx.x; // W2: HID rows x F_OUT cols -> w2t[F_OUT][HID]
        if (t < HID * F_OUT) {
            int n = t / HID, k = t - n * HID;
            w2t[t] = f2bf(W2[(size_t)k * F_OUT + n]);
        }
    }
}

// Fused: per-block sum of deg -> bsums, plus dinv[i] = rsqrt(deg+1).
__global__ __launch_bounds__(256) void scan_reduce_dinv(const int* __restrict__ deg,
                                                        int* __restrict__ bsums,
                                                        float* __restrict__ dinv, int N) {
    int i = blockIdx.x * 256 + threadIdx.x;
    int v = (i < N) ? deg[i] : 0;
    if (i < N) dinv[i] = rsqrtf((float)(v + 1));   // +1 = self loop
#pragma unroll
    for (int ofs = 32; ofs > 0; ofs >>= 1) v += __shfl_down(v, ofs);
    __shared__ int ws[4];
    if ((threadIdx.x & 63) == 0) ws[threadIdx.x >> 6] = v;
    __syncthreads();
    if (threadIdx.x == 0) bsums[blockIdx.x] = ws[0] + ws[1] + ws[2] + ws[3];
}

// Fused: blocks [0,nb): redundant LDS scan of bsums + intra-block scan of deg -> off;
// blocks [nb, ...): xs = bf16(dinv * x)  (dinv ready since scan_reduce_dinv).
__global__ __launch_bounds__(256) void scan_final_scalex(const int* __restrict__ deg,
                                                         const int* __restrict__ bsums,
                                                         int* __restrict__ off, int N, int nb,
                                                         const float* __restrict__ x,
                                                         const float* __restrict__ dinv,
                                                         unsigned short* __restrict__ xs) {
    const int tid = threadIdx.x;
    if ((int)blockIdx.x >= nb) {   // scalex partition
        int i = (blockIdx.x - nb) * 256 + tid;     // one thread per 8 elems
        if (i < N_NODES * F_IN / 8) {
            float dv = dinv[i >> 4];
            float4 v0 = ((const float4*)x)[i * 2];
            float4 v1 = ((const float4*)x)[i * 2 + 1];
            short8 o;
            o[0] = (short)f2bf(v0.x * dv); o[1] = (short)f2bf(v0.y * dv);
            o[2] = (short)f2bf(v0.z * dv); o[3] = (short)f2bf(v0.w * dv);
            o[4] = (short)f2bf(v1.x * dv); o[5] = (short)f2bf(v1.y * dv);
            o[6] = (short)f2bf(v1.z * dv); o[7] = (short)f2bf(v1.w * dv);
            *(short8*)(xs + (size_t)i * 8) = o;
        }
        return;
    }
    __shared__ int bs[256];
    __shared__ int s[256];
    bs[tid] = (tid < nb) ? bsums[tid] : 0;
    const int i = blockIdx.x * 256 + tid;
    int v = (i < N) ? deg[i] : 0;
    s[tid] = v;
    __syncthreads();
    for (int ofs = 1; ofs < 256; ofs <<= 1) {
        int tb = (tid >= ofs) ? bs[tid - ofs] : 0;
        int tv = (tid >= ofs) ? s[tid - ofs] : 0;
        __syncthreads();
        bs[tid] += tb;
        s[tid] += tv;
        __syncthreads();
    }
    int bbase = (blockIdx.x == 0) ? 0 : bs[blockIdx.x - 1];
    int excl = (tid == 0) ? 0 : s[tid - 1];
    if (i <= N) off[i] = bbase + excl;
}

// Pure scatter: csr[off[dst] + pos] = src.  No atomics.
__global__ void scatter_kernel(const int* __restrict__ src, const int* __restrict__ dst,
                               const int* __restrict__ pos, const int* __restrict__ off,
                               int* __restrict__ csr, int E) {
    int i = blockIdx.x * blockDim.x + threadIdx.x;
    if (i < E) csr[off[dst[i]] + pos[i]] = src[i];
}

// Wave-per-node aggregation over 128-dim bf16 rows, fp32 accumulate.
// Wave = 4 edge-slots x 16 lanes (ushort8 / 16 B per lane); 4 nodes per 256-block.
// Predicated-batch loop: each batch issues 4 clamped loads per slot (16 per wave).
// MODE 0: out_bf16[n] = bf16( dinv[n] * (self + sum) )
// MODE 1: out_f32[n]  = dinv[n] * (self + sum) + bias
template <int MODE>
__global__ __launch_bounds__(256) void agg_bf16(const unsigned short* __restrict__ hs,
                                                const int* __restrict__ off,
                                                const int* __restrict__ csr,
                                                const float* __restrict__ dinv,
                                                const float* __restrict__ bias,
                                                void* __restrict__ outp, int N) {
    const int wid = threadIdx.x >> 6;
    const int n = blockIdx.x * 4 + wid;
    if (n >= N) return;
    const int lane = threadIdx.x & 63;
    const int lane16 = lane & 15;
    const int slot = lane >> 4;   // 0..3

    float va[8], vb[8], vc[8], vd[8];
#pragma unroll
    for (int j = 0; j < 8; j++) { va[j] = 0.f; vb[j] = 0.f; vc[j] = 0.f; vd[j] = 0.f; }

    if (slot == 0) {  // self loop
        short8 s = *(const short8*)(hs + (size_t)n * 128 + lane16 * 8);
#pragma unroll
        for (int j = 0; j < 8; j++) va[j] = bf2f((unsigned short)s[j]);
    }

    const int e0 = off[n];
    const int e1 = off[n + 1];
    for (int e = e0 + slot; e < e1; e += 16) {
        const int i1 = e + 4, i2 = e + 8, i3 = e + 12;
        const float f1 = (i1 < e1) ? 1.f : 0.f;
        const float f2 = (i2 < e1) ? 1.f : 0.f;
        const float f3 = (i3 < e1) ? 1.f : 0.f;
        const int c1 = min(i1, e1 - 1), c2 = min(i2, e1 - 1), c3 = min(i3, e1 - 1);
        int s0 = csr[e];
        int s1 = csr[c1];
        int s2 = csr[c2];
        int s3 = csr[c3];
        short8 v0 = *(const short8*)(hs + (size_t)s0 * 128 + lane16 * 8);
        short8 v1 = *(const short8*)(hs + (size_t)s1 * 128 + lane16 * 8);
        short8 v2 = *(const short8*)(hs + (size_t)s2 * 128 + lane16 * 8);
        short8 v3 = *(const short8*)(hs + (size_t)s3 * 128 + lane16 * 8);
#pragma unroll
        for (int j = 0; j < 8; j++) va[j] += bf2f((unsigned short)v0[j]);
#pragma unroll
        for (int j = 0; j < 8; j++) vb[j] = fmaf(f1, bf2f((unsigned short)v1[j]), vb[j]);
#pragma unroll
        for (int j = 0; j < 8; j++) vc[j] = fmaf(f2, bf2f((unsigned short)v2[j]), vc[j]);
#pragma unroll
        for (int j = 0; j < 8; j++) vd[j] = fmaf(f3, bf2f((unsigned short)v3[j]), vd[j]);
    }
#pragma unroll
    for (int j = 0; j < 8; j++) va[j] += vb[j] + vc[j] + vd[j];

#pragma unroll
    for (int j = 0; j < 8; j++) va[j] += __shfl_down(va[j], 32);
#pragma unroll
    for (int j = 0; j < 8; j++) va[j] += __shfl_down(va[j], 16);

    if (lane < 16) {
        float dv = dinv[n];
        if (MODE == 0) {
            short8 o;
#pragma unroll
            for (int j = 0; j < 8; j++) o[j] = (short)f2bf(va[j] * dv);
            *(short8*)((unsigned short*)outp + (size_t)n * 128 + lane * 8) = o;
        } else {
            float* op = (float*)outp + (size_t)n * 128 + lane * 8;
            float4 o0, o1;
            o0.x = va[0] * dv + bias[lane * 8 + 0];
            o0.y = va[1] * dv + bias[lane * 8 + 1];
            o0.z = va[2] * dv + bias[lane * 8 + 2];
            o0.w = va[3] * dv + bias[lane * 8 + 3];
            o1.x = va[4] * dv + bias[lane * 8 + 4];
            o1.y = va[5] * dv + bias[lane * 8 + 5];
            o1.z = va[6] * dv + bias[lane * 8 + 6];
            o1.w = va[7] * dv + bias[lane * 8 + 7];
            ((float4*)op)[0] = o0;
            ((float4*)op)[1] = o1;
        }
    }
}

// Fused double GEMM: hs2 = dinv * ( relu(Y@W1 + b1) @ W2 ), per 64-row block.
// Phase A (K=128, NC=256): Y from global, W1^T from global; h2 tile -> LDS (pitch 264).
// Phase B (K=256, NC=128): A frags from LDS (ds_read_b128, 2-way bank alias = free),
// W2^T from global; epilogue *dinv -> global bf16.
// Wave split both phases: rowgrp = wid&1 (32 rows), colgrp = wid>>1 (half the cols).
// Frag layouts: A/B m(n)=lane&15, k=q*8+j;  D col=lane&15, row=q*4+reg.
__global__ __launch_bounds__(256) void gemm12(const unsigned short* __restrict__ Y,
                                              const unsigned short* __restrict__ w1t,
                                              const float* __restrict__ b1,
                                              const unsigned short* __restrict__ w2t,
                                              const float* __restrict__ dinv,
                                              unsigned short* __restrict__ hs2, int M) {
    __shared__ unsigned short h2s[64 * H2P];   // 33792 B

    const int wid = threadIdx.x >> 6;
    const int lane = threadIdx.x & 63;
    const int an = lane & 15;
    const int q = lane >> 4;
    const int rowgrp = wid & 1;
    const int colgrp = wid >> 1;
    const int m0 = blockIdx.x * 64 + rowgrp * 32;
    const int lrow0 = rowgrp * 32;

    // ---- Phase A: h2 = relu(Y@W1+b1) -> LDS ----
    {
        short8 a[2][4];
#pragma unroll
        for (int r = 0; r < 2; r++) {
            int row = m0 + r * 16 + an;
            if (row >= M) row = M - 1;
            const unsigned short* xp = Y + (size_t)row * F_IN + q * 8;
#pragma unroll
            for (int c = 0; c < 4; c++) a[r][c] = *(const short8*)(xp + c * 32);
        }
#pragma unroll 4
        for (int t = 0; t < 8; t++) {                     // 8 col tiles of 16 -> 128 cols/wave
            const int col = (colgrp * 8 + t) * 16 + an;
            const unsigned short* wp = w1t + (size_t)col * F_IN + q * 8;
            short8 b[4];
#pragma unroll
            for (int c = 0; c < 4; c++) b[c] = *(const short8*)(wp + c * 32);
            f32x4 acc0 = {0.f, 0.f, 0.f, 0.f};
            f32x4 acc1 = {0.f, 0.f, 0.f, 0.f};
#pragma unroll
            for (int c = 0; c < 4; c++) {
                acc0 = __builtin_amdgcn_mfma_f32_16x16x32_bf16(a[0][c], b[c], acc0, 0, 0, 0);
                acc1 = __builtin_amdgcn_mfma_f32_16x16x32_bf16(a[1][c], b[c], acc1, 0, 0, 0);
            }
            const float bv = b1[col];
#pragma unroll
            for (int rr = 0; rr < 4; rr++) {
                h2s[(lrow0 + q * 4 + rr) * H2P + col]      = f2bf(fmaxf(acc0[rr] + bv, 0.f));
                h2s[(lrow0 + 16 + q * 4 + rr) * H2P + col] = f2bf(fmaxf(acc1[rr] + bv, 0.f));
            }
        }
    }
    __syncthreads();

    // ---- Phase B: hs2 = dinv * (h2 @ W2) ----
    {
        short8 a[2][8];
#pragma unroll
        for (int r = 0; r < 2; r++) {
            const unsigned short* hp = &h2s[(lrow0 + r * 16 + an) * H2P + q * 8];
#pragma unroll
            for (int c = 0; c < 8; c++) a[r][c] = *(const short8*)(hp + c * 32);
        }
#pragma unroll 2
        for (int t = 0; t < 4; t++) {                     // 4 col tiles of 16 -> 64 cols/wave
            const int col = (colgrp * 4 + t) * 16 + an;
            const unsigned short* wp = w2t + (size_t)col * HID + q * 8;
            short8 b[8];
#pragma unroll
            for (int c = 0; c < 8; c++) b[c] = *(const short8*)(wp + c * 32);
            f32x4 acc0 = {0.f, 0.f, 0.f, 0.f};
            f32x4 acc1 = {0.f, 0.f, 0.f, 0.f};
#pragma unroll
            for (int c = 0; c < 8; c++) {
                acc0 = __builtin_amdgcn_mfma_f32_16x16x32_bf16(a[0][c], b[c], acc0, 0, 0, 0);
                acc1 = __builtin_amdgcn_mfma_f32_16x16x32_bf16(a[1][c], b[c], acc1, 0, 0, 0);
            }
#pragma unroll
            for (int rr = 0; rr < 4; rr++) {
                int m = m0 + q * 4 + rr;
                if (m < M) hs2[(size_t)m * F_OUT + col] = f2bf(acc0[rr] * dinv[m]);
                int m2 = m0 + 16 + q * 4 + rr;
                if (m2 < M) hs2[(size_t)m2 * F_OUT + col] = f2bf(acc1[rr] * dinv[m2]);
            }
        }
    }
}

extern "C" void kernel_launch(void* const* d_in, const int* in_sizes, int n_in,
                              void* d_out, int out_size, void* d_ws, size_t ws_size,
                              hipStream_t stream) {
    const float* x  = (const float*)d_in[0];
    const int*   ei = (const int*)d_in[1];   // [2,E] int32
    const float* W1 = (const float*)d_in[2];
    const float* b1 = (const float*)d_in[3];
    const float* W2 = (const float*)d_in[4];
    const float* b2 = (const float*)d_in[5];

    const int N = N_NODES;
    const int E = N_EDGES;
    const int* srcp = ei;
    const int* dstp = ei + E;

    char* base = (char*)d_ws;
    size_t o = 0;
    auto alloc = [&](size_t bytes) {
        void* p = base + o;
        o = (o + bytes + 255) & ~(size_t)255;
        return p;
    };
    int*            deg  = (int*)alloc((size_t)N * 4);
    int*            offs = (int*)alloc((size_t)(N + 1) * 4);
    float*          dinv = (float*)alloc((size_t)N * 4);
    int*            bsum = (int*)alloc(256 * 4);
    int*            pos  = (int*)alloc((size_t)E * 4);
    int*            csr  = (int*)alloc((size_t)E * 4);
    unsigned short* xs   = (unsigned short*)alloc((size_t)N * F_IN * 2);  // dinv*x, bf16
    unsigned short* Y    = (unsigned short*)alloc((size_t)N * F_IN * 2);  // A_hat@X, bf16
    unsigned short* w1t  = (unsigned short*)alloc((size_t)F_IN * HID * 2);
    unsigned short* w2t  = (unsigned short*)alloc((size_t)HID * F_OUT * 2);
    unsigned short* hs2  = xs;  // xs dead after agg1

    hipMemsetAsync(deg, 0, (size_t)N * 4, stream);

    const int NB  = (N + 256) / 256;           // 196, covers i==N in scan_final
    const int NBX = (N * F_IN / 8 + 255) / 256;
    const int EB  = (E + 255) / 256;
    const int NB1 = (F_IN * HID + 255) / 256;
    const int NB2 = (HID * F_OUT + 255) / 256;

    deg_wt_kernel<<<EB + NB1 + NB2, 256, 0, stream>>>(dstp, deg, pos, E, W1, w1t, W2, w2t, EB, NB1);
    scan_reduce_dinv<<<NB, 256, 0, stream>>>(deg, bsum, dinv, N);
    scan_final_scalex<<<NB + NBX, 256, 0, stream>>>(deg, bsum, offs, N, NB, x, dinv, xs);
    scatter_kernel<<<EB, 256, 0, stream>>>(srcp, dstp, pos, offs, csr, E);

    // layer 1 agg: Y = A_hat@X (bf16 gather)
    agg_bf16<0><<<(N + 3) / 4, 256, 0, stream>>>(xs, offs, csr, dinv, nullptr, Y, N);
    // fused GEMMs: hs2 = dinv * ( relu(Y@W1+b1) @ W2 )
    gemm12<<<(N + 63) / 64, 256, 0, stream>>>(Y, w1t, b1, w2t, dinv, hs2, N);
    // layer 2 agg: out = dinv*(hs2[self]+gather) + b2
    agg_bf16<1><<<(N + 3) / 4, 256, 0, stream>>>(hs2, offs, csr, dinv, b2, d_out, N);
}